// Round 2
// baseline (286.720 us; speedup 1.0000x reference)
//
#include <hip/hip_runtime.h>

#define NNODES 50000
#define MPAD   50048    // padded to multiple of 128 for MFMA tiles
#define NEDGES 800000
#define KDIM   256      // in/hidden feature dim (GEMM K)
#define FH     256      // hidden feats
#define FOUT   128      // out feats

// ---- counting-sort geometry ----
#define SHIFT  8
#define NBUCK  196              // ceil(50000/256); max dst>>8 = 195
#define NB1    200              // level-1 blocks
#define EPB    4000             // edges per level-1 block (NB1*EPB == NEDGES)
#define CELLS  (NBUCK * NB1)    // 39200 per side
#define NSCAN  (2 * CELLS)      // 78400 (dst cells | src cells)
#define SCANB  ((NSCAN + 511) / 512)   // 154

typedef __bf16 bf16x8 __attribute__((ext_vector_type(8)));
typedef float floatx4 __attribute__((ext_vector_type(4)));

// ---------------- bf16 helpers (RNE) ----------------
__device__ __forceinline__ float bf2f(unsigned short u) {
    union { unsigned int i; float f; } v;
    v.i = ((unsigned int)u) << 16;
    return v.f;
}
__device__ __forceinline__ unsigned short f2bf(float f) {
    union { float f; unsigned int i; } v;
    v.f = f;
    unsigned int r = v.i + 0x7FFFu + ((v.i >> 16) & 1u);
    return (unsigned short)(r >> 16);
}

// ---------------- fused: level-1 histograms (blocks 0..NB1-1) + W transpose/cast (NB1..NB1+95)
__global__ __launch_bounds__(256) void l1_count_cast(const int* __restrict__ src,
                                                     const int* __restrict__ dst,
                                                     int* __restrict__ cell,
                                                     const float* __restrict__ W1,
                                                     unsigned short* __restrict__ Wt1,
                                                     const float* __restrict__ W2,
                                                     unsigned short* __restrict__ Wt2) {
    __shared__ int histD[256], histS[256];
    __shared__ float tile[32][33];
    const int tid = threadIdx.x;

    if (blockIdx.x >= NB1) {
        // ---- W1,W2 [K][N] -> Wt [N][K] bf16, LDS 32x32 transpose ----
        int b = blockIdx.x - NB1;
        const float* W; unsigned short* Wt; int N;
        if (b < 64) { W = W1; Wt = Wt1; N = FH; }
        else        { b -= 64; W = W2; Wt = Wt2; N = FOUT; }
        int kt = (b & 7) * 32;
        int nt = (b >> 3) * 32;
        int tx = tid & 31;
        int ty = tid >> 5;
        for (int r = ty; r < 32; r += 8)
            tile[r][tx] = W[(size_t)(kt + r) * N + nt + tx];
        __syncthreads();
        for (int r = ty; r < 32; r += 8)
            Wt[(size_t)(nt + r) * KDIM + kt + tx] = f2bf(tile[tx][r]);
        return;
    }

    const int b = blockIdx.x;
    const int base = b * EPB;
    histD[tid] = 0; histS[tid] = 0;
    __syncthreads();
    for (int g = tid; g < EPB / 4; g += 256) {
        uint4 s4 = *(const uint4*)(src + base + g * 4);
        uint4 d4 = *(const uint4*)(dst + base + g * 4);
        atomicAdd(&histD[d4.x >> SHIFT], 1);
        atomicAdd(&histD[d4.y >> SHIFT], 1);
        atomicAdd(&histD[d4.z >> SHIFT], 1);
        atomicAdd(&histD[d4.w >> SHIFT], 1);
        atomicAdd(&histS[s4.x >> SHIFT], 1);
        atomicAdd(&histS[s4.y >> SHIFT], 1);
        atomicAdd(&histS[s4.z >> SHIFT], 1);
        atomicAdd(&histS[s4.w >> SHIFT], 1);
    }
    __syncthreads();
    if (tid < NBUCK) {
        cell[tid * NB1 + b] = histD[tid];
        cell[CELLS + tid * NB1 + b] = histS[tid];
    }
}

// ---------------- generic 3-kernel exclusive scan ----------------
__global__ __launch_bounds__(512) void scanA(int* __restrict__ data,
                                             int* __restrict__ sums, int n) {
    __shared__ int s[512];
    int tid = threadIdx.x;
    int i = blockIdx.x * 512 + tid;
    int v = (i < n) ? data[i] : 0;
    s[tid] = v;
    __syncthreads();
    for (int off = 1; off < 512; off <<= 1) {
        int t = (tid >= off) ? s[tid - off] : 0;
        __syncthreads();
        s[tid] += t;
        __syncthreads();
    }
    if (i < n) data[i] = s[tid] - v;
    if (tid == 511) sums[blockIdx.x] = s[511];
}

__global__ __launch_bounds__(512) void scanB(int* __restrict__ sums, int nb) {
    __shared__ int s[512];
    int tid = threadIdx.x;
    int v = (tid < nb) ? sums[tid] : 0;
    s[tid] = v;
    __syncthreads();
    for (int off = 1; off < 512; off <<= 1) {
        int t = (tid >= off) ? s[tid - off] : 0;
        __syncthreads();
        s[tid] += t;
        __syncthreads();
    }
    if (tid < nb) sums[tid] = s[tid] - v;
}

__global__ __launch_bounds__(512) void scanC(int* __restrict__ data,
                                             const int* __restrict__ sums, int n) {
    int i = blockIdx.x * 512 + threadIdx.x;
    if (i < n) data[i] += sums[blockIdx.x];
}

// ---------------- level-1 scatter: in-block counting sort, coalesced global writes --------
__global__ __launch_bounds__(256) void l1_scatter(const int* __restrict__ src,
                                                  const int* __restrict__ dst,
                                                  const int* __restrict__ cell,  // scanned
                                                  unsigned int* __restrict__ tmp1,
                                                  unsigned char* __restrict__ tmp2) {
    __shared__ int histD[256], histS[256];
    __shared__ int exD[256], exS[256];
    __shared__ unsigned int bufD[EPB];
    __shared__ unsigned short bufS[EPB];
    const int b = blockIdx.x, tid = threadIdx.x;
    const int base = b * EPB;

    histD[tid] = 0; histS[tid] = 0;
    __syncthreads();
    for (int g = tid; g < EPB / 4; g += 256) {
        uint4 s4 = *(const uint4*)(src + base + g * 4);
        uint4 d4 = *(const uint4*)(dst + base + g * 4);
        atomicAdd(&histD[d4.x >> SHIFT], 1);
        atomicAdd(&histD[d4.y >> SHIFT], 1);
        atomicAdd(&histD[d4.z >> SHIFT], 1);
        atomicAdd(&histD[d4.w >> SHIFT], 1);
        atomicAdd(&histS[s4.x >> SHIFT], 1);
        atomicAdd(&histS[s4.y >> SHIFT], 1);
        atomicAdd(&histS[s4.z >> SHIFT], 1);
        atomicAdd(&histS[s4.w >> SHIFT], 1);
    }
    __syncthreads();
    int vD = histD[tid], vS = histS[tid];
    exD[tid] = vD; exS[tid] = vS;
    __syncthreads();
    for (int off = 1; off < 256; off <<= 1) {
        int tD = (tid >= off) ? exD[tid - off] : 0;
        int tS = (tid >= off) ? exS[tid - off] : 0;
        __syncthreads();
        exD[tid] += tD; exS[tid] += tS;
        __syncthreads();
    }
    int eD = exD[tid] - vD, eS = exS[tid] - vS;
    __syncthreads();
    exD[tid] = eD; exS[tid] = eS;
    histD[tid] = eD; histS[tid] = eS;
    __syncthreads();
    for (int g = tid; g < EPB / 4; g += 256) {
        uint4 s4 = *(const uint4*)(src + base + g * 4);
        uint4 d4 = *(const uint4*)(dst + base + g * 4);
        unsigned int ss[4] = {s4.x, s4.y, s4.z, s4.w};
        unsigned int dd[4] = {d4.x, d4.y, d4.z, d4.w};
#pragma unroll
        for (int j = 0; j < 4; ++j) {
            int p = atomicAdd(&histD[dd[j] >> SHIFT], 1);
            bufD[p] = (ss[j] << 16) | dd[j];
            int q = atomicAdd(&histS[ss[j] >> SHIFT], 1);
            bufS[q] = (unsigned short)ss[j];
        }
    }
    __syncthreads();
    for (int e = tid; e < EPB; e += 256) {
        unsigned int p = bufD[e];
        int k = (p & 0xFFFFu) >> SHIFT;
        tmp1[cell[k * NB1 + b] + (e - exD[k])] = p;
    }
    for (int e = tid; e < EPB; e += 256) {
        unsigned int s = bufS[e];
        int k = s >> SHIFT;
        tmp2[(cell[CELLS + k * NB1 + b] - NEDGES) + (e - exS[k])] = (unsigned char)(s & 255u);
    }
}

// ---------------- fused level-2: dst (blocks 0..NBUCK-1) + src (NBUCK..2*NBUCK-1) ---------
__global__ __launch_bounds__(256) void l2_both(const unsigned int* __restrict__ tmp1,
                                               const unsigned char* __restrict__ tmp2,
                                               const int* __restrict__ cell,
                                               int* __restrict__ row_ptr,
                                               float* __restrict__ norm_dst,
                                               float* __restrict__ norm_src,
                                               int* __restrict__ csr_src) {
    __shared__ int cnt[256], ofs[256], cur[256];
    const int tid = threadIdx.x;

    if (blockIdx.x >= NBUCK) {
        // ---- src side: counts -> norm_src ----
        const int k = blockIdx.x - NBUCK;
        const int start = cell[CELLS + k * NB1] - NEDGES;
        const int end = (k + 1 < NBUCK) ? cell[CELLS + (k + 1) * NB1] - NEDGES : NEDGES;
        cnt[tid] = 0;
        __syncthreads();
        for (int e = start + tid; e < end; e += 256)
            atomicAdd(&cnt[tmp2[e]], 1);
        __syncthreads();
        int node = k * 256 + tid;
        if (node < NNODES) {
            int d = cnt[tid] < 1 ? 1 : cnt[tid];
            norm_src[node] = 1.0f / sqrtf((float)d);
        }
        return;
    }

    // ---- dst side: exact counts + row_ptr + norm_dst + csr scatter ----
    const int k = blockIdx.x;
    const int start = cell[k * NB1];
    const int end = (k + 1 < NBUCK) ? cell[(k + 1) * NB1] : NEDGES;
    cnt[tid] = 0;
    __syncthreads();
    for (int e = start + tid; e < end; e += 256)
        atomicAdd(&cnt[tmp1[e] & 255u], 1);
    __syncthreads();
    int v = cnt[tid];
    ofs[tid] = v;
    __syncthreads();
    for (int off = 1; off < 256; off <<= 1) {
        int t = (tid >= off) ? ofs[tid - off] : 0;
        __syncthreads();
        ofs[tid] += t;
        __syncthreads();
    }
    int excl = ofs[tid] - v;
    int node = k * 256 + tid;
    if (node < NNODES) {
        row_ptr[node] = start + excl;
        int d = v < 1 ? 1 : v;
        norm_dst[node] = 1.0f / sqrtf((float)d);
    }
    cur[tid] = start + excl;
    if (k == 0 && tid == 0) row_ptr[NNODES] = NEDGES;
    __syncthreads();
    for (int e = start + tid; e < end; e += 256) {
        unsigned int p = tmp1[e];
        int pos = atomicAdd(&cur[p & 255u], 1);
        csr_src[pos] = (int)(p >> 16);
    }
}

// ---------------- A-staging loaders (8 bf16 = 16B, packed in uint4) ----------------
__device__ __forceinline__ uint4 stage_a8(const float* A, int row, int k, float scale, bool valid) {
    if (!valid) return make_uint4(0u, 0u, 0u, 0u);
    const float* p = A + (size_t)row * KDIM + k;
    float4 v0 = *(const float4*)p;
    float4 v1 = *(const float4*)(p + 4);
    union { uint4 u; unsigned short s[8]; } r;
    r.s[0] = f2bf(v0.x * scale); r.s[1] = f2bf(v0.y * scale);
    r.s[2] = f2bf(v0.z * scale); r.s[3] = f2bf(v0.w * scale);
    r.s[4] = f2bf(v1.x * scale); r.s[5] = f2bf(v1.y * scale);
    r.s[6] = f2bf(v1.z * scale); r.s[7] = f2bf(v1.w * scale);
    return r.u;
}
__device__ __forceinline__ uint4 stage_a8(const unsigned short* A, int row, int k, float, bool) {
    return *(const uint4*)(A + (size_t)row * KDIM + k);
}

// ---------------- bf16 MFMA GEMM: C[M, NT*128] = (A[M,256] * norm?) @ Bt^T ----------------
// NT = number of 128-col tiles this block covers. NT=2 => one pass over A for N=256
// (halves the A fetch vs grid.y=2, since A doesn't survive in L2 between y-blocks).
template <typename TA, bool SCALE, int NT>
__global__ __launch_bounds__(256) void gemm_mfma(const TA* __restrict__ A,
                                                 const unsigned short* __restrict__ Bt,
                                                 const float* __restrict__ norm,
                                                 unsigned short* __restrict__ C,
                                                 int N) {
    __shared__ __align__(16) unsigned short As[128][32];
    __shared__ __align__(16) unsigned short Bs[128 * NT][32];

    const int tid = threadIdx.x;
    const int lane = tid & 63;
    const int wave = tid >> 6;
    const int wm = wave & 1, wn = wave >> 1;
    const int m0 = blockIdx.x * 128;
    const int n0 = blockIdx.y * (128 * NT);

    const int srow = tid >> 2;
    const int sk = (tid & 3) << 3;

    const int r0 = m0 + srow;
    const int r1 = r0 + 64;
    bool va0 = true, va1 = true;
    float sc0 = 0.f, sc1 = 0.f;
    if (SCALE) {
        va0 = (r0 < NNODES); va1 = (r1 < NNODES);
        sc0 = va0 ? norm[r0] : 0.f;
        sc1 = va1 ? norm[r1] : 0.f;
    }

    const unsigned short* Bg = Bt + (size_t)(n0 + srow) * KDIM + sk;

    floatx4 acc[NT][4][4] = {};

    const int ar = wm * 64 + (lane & 15);
    const int br = wn * 64 + (lane & 15);
    const int fk = (lane >> 4) << 3;

    for (int kk = 0; kk < KDIM; kk += 32) {
        uint4 a0 = stage_a8(A, va0 ? r0 : 0, kk + sk, sc0, va0);
        uint4 a1 = stage_a8(A, va1 ? r1 : 0, kk + sk, sc1, va1);
        uint4 bld[2 * NT];
#pragma unroll
        for (int t = 0; t < 2 * NT; ++t)
            bld[t] = *(const uint4*)(Bg + (size_t)(64 * t) * KDIM + kk);
        __syncthreads();
        *(uint4*)&As[srow][sk] = a0;
        *(uint4*)&As[srow + 64][sk] = a1;
#pragma unroll
        for (int t = 0; t < 2 * NT; ++t)
            *(uint4*)&Bs[srow + 64 * t][sk] = bld[t];
        __syncthreads();

        bf16x8 af[4];
#pragma unroll
        for (int i = 0; i < 4; ++i)
            af[i] = *(const bf16x8*)&As[ar + i * 16][fk];
#pragma unroll
        for (int t = 0; t < NT; ++t) {
            bf16x8 bfr[4];
#pragma unroll
            for (int j = 0; j < 4; ++j)
                bfr[j] = *(const bf16x8*)&Bs[t * 128 + br + j * 16][fk];
#pragma unroll
            for (int i = 0; i < 4; ++i)
#pragma unroll
                for (int j = 0; j < 4; ++j)
                    acc[t][i][j] = __builtin_amdgcn_mfma_f32_16x16x32_bf16(af[i], bfr[j], acc[t][i][j], 0, 0, 0);
        }
    }

    const int rb = (lane >> 4) << 2;
    const int cc = lane & 15;
#pragma unroll
    for (int t = 0; t < NT; ++t) {
#pragma unroll
        for (int i = 0; i < 4; ++i) {
            int mb = m0 + wm * 64 + i * 16 + rb;
#pragma unroll
            for (int j = 0; j < 4; ++j) {
                int col = n0 + t * 128 + wn * 64 + j * 16 + cc;
#pragma unroll
                for (int r = 0; r < 4; ++r) {
                    int m = mb + r;
                    if (m < NNODES)
                        C[(size_t)m * N + col] = f2bf(acc[t][i][j][r]);
                }
            }
        }
    }
}

// ---------------- agg layer 1: bf16 in (F=256), bf16 out. Full row per wave,
// 8-deep + 4-deep + scalar unroll. h1 = relu(agg*norm_dst+b1)*norm_src; pad rows zero.
__global__ __launch_bounds__(256) void agg1_kernel(const unsigned short* __restrict__ H,
                                                   const int* __restrict__ row_ptr,
                                                   const int* __restrict__ csr_src,
                                                   const float* __restrict__ norm_dst,
                                                   const float* __restrict__ norm_src,
                                                   const float* __restrict__ bias,
                                                   unsigned short* __restrict__ out) {
    const int F = 256;
    int node = blockIdx.x * 4 + (threadIdx.x >> 6);
    int lane = threadIdx.x & 63;
    int f0 = lane * 4;
    if (node >= NNODES) {
        if (node < MPAD) {
            ushort4 z = {0, 0, 0, 0};
            *(ushort4*)(out + (size_t)node * F + f0) = z;
        }
        return;
    }
    int e0 = row_ptr[node];
    int e1 = row_ptr[node + 1];

    float acc0 = 0.f, acc1 = 0.f, acc2 = 0.f, acc3 = 0.f;
    const unsigned short* Hl = H + f0;

    int e = e0;
    for (; e + 7 < e1; e += 8) {
        ushort4 v[8];
#pragma unroll
        for (int u = 0; u < 8; ++u)
            v[u] = *(const ushort4*)(Hl + (size_t)csr_src[e + u] * F);
#pragma unroll
        for (int u = 0; u < 8; ++u) {
            acc0 += bf2f(v[u].x); acc1 += bf2f(v[u].y);
            acc2 += bf2f(v[u].z); acc3 += bf2f(v[u].w);
        }
    }
    for (; e + 3 < e1; e += 4) {
        ushort4 v[4];
#pragma unroll
        for (int u = 0; u < 4; ++u)
            v[u] = *(const ushort4*)(Hl + (size_t)csr_src[e + u] * F);
#pragma unroll
        for (int u = 0; u < 4; ++u) {
            acc0 += bf2f(v[u].x); acc1 += bf2f(v[u].y);
            acc2 += bf2f(v[u].z); acc3 += bf2f(v[u].w);
        }
    }
    for (; e < e1; ++e) {
        ushort4 v = *(const ushort4*)(Hl + (size_t)csr_src[e] * F);
        acc0 += bf2f(v.x); acc1 += bf2f(v.y); acc2 += bf2f(v.z); acc3 += bf2f(v.w);
    }

    float nd = norm_dst[node];
    float ns = norm_src[node];
    float o0 = fmaxf(fmaf(acc0, nd, bias[f0 + 0]), 0.0f) * ns;
    float o1 = fmaxf(fmaf(acc1, nd, bias[f0 + 1]), 0.0f) * ns;
    float o2 = fmaxf(fmaf(acc2, nd, bias[f0 + 2]), 0.0f) * ns;
    float o3 = fmaxf(fmaf(acc3, nd, bias[f0 + 3]), 0.0f) * ns;
    ushort4 o;
    o.x = f2bf(o0); o.y = f2bf(o1); o.z = f2bf(o2); o.w = f2bf(o3);
    *(ushort4*)(out + (size_t)node * F + f0) = o;
}

// ---------------- agg layer 2: bf16 in (F=128), fp32 out, no relu. Half-wave per node. ----
__global__ __launch_bounds__(256) void agg2_kernel(const unsigned short* __restrict__ H,
                                                   const int* __restrict__ row_ptr,
                                                   const int* __restrict__ csr_src,
                                                   const float* __restrict__ norm_dst,
                                                   const float* __restrict__ bias,
                                                   float* __restrict__ out) {
    const int F = 128;
    int node = blockIdx.x * 8 + (threadIdx.x >> 5);
    if (node >= NNODES) return;
    int lane = threadIdx.x & 31;
    int f0 = lane * 4;
    int e0 = row_ptr[node];
    int e1 = row_ptr[node + 1];

    float acc0 = 0.f, acc1 = 0.f, acc2 = 0.f, acc3 = 0.f;
    const unsigned short* Hl = H + f0;

    int e = e0;
    for (; e + 7 < e1; e += 8) {
        ushort4 v[8];
#pragma unroll
        for (int u = 0; u < 8; ++u)
            v[u] = *(const ushort4*)(Hl + (size_t)csr_src[e + u] * F);
#pragma unroll
        for (int u = 0; u < 8; ++u) {
            acc0 += bf2f(v[u].x); acc1 += bf2f(v[u].y);
            acc2 += bf2f(v[u].z); acc3 += bf2f(v[u].w);
        }
    }
    for (; e + 3 < e1; e += 4) {
        ushort4 v[4];
#pragma unroll
        for (int u = 0; u < 4; ++u)
            v[u] = *(const ushort4*)(Hl + (size_t)csr_src[e + u] * F);
#pragma unroll
        for (int u = 0; u < 4; ++u) {
            acc0 += bf2f(v[u].x); acc1 += bf2f(v[u].y);
            acc2 += bf2f(v[u].z); acc3 += bf2f(v[u].w);
        }
    }
    for (; e < e1; ++e) {
        ushort4 v = *(const ushort4*)(Hl + (size_t)csr_src[e] * F);
        acc0 += bf2f(v.x); acc1 += bf2f(v.y); acc2 += bf2f(v.z); acc3 += bf2f(v.w);
    }

    float nd = norm_dst[node];
    float4 o;
    o.x = fmaf(acc0, nd, bias[f0 + 0]);
    o.y = fmaf(acc1, nd, bias[f0 + 1]);
    o.z = fmaf(acc2, nd, bias[f0 + 2]);
    o.w = fmaf(acc3, nd, bias[f0 + 3]);
    *(float4*)(out + (size_t)node * F + f0) = o;
}

// ---------------- launch ----------------
extern "C" void kernel_launch(void* const* d_in, const int* in_sizes, int n_in,
                              void* d_out, int out_size, void* d_ws, size_t ws_size,
                              hipStream_t stream) {
    const float* x   = (const float*)d_in[0];
    const int*   src = (const int*)d_in[1];
    const int*   dst = (const int*)d_in[2];
    const float* W1  = (const float*)d_in[3];
    const float* b1  = (const float*)d_in[4];
    const float* W2  = (const float*)d_in[5];
    const float* b2  = (const float*)d_in[6];
    float* out = (float*)d_out;

    char* ws = (char*)d_ws;
    size_t off = 0;
    auto alloc = [&](size_t bytes) {
        char* p = ws + off;
        off += (bytes + 255) & ~(size_t)255;
        return p;
    };
    float* norm_src  = (float*)alloc(NNODES * 4);
    float* norm_dst  = (float*)alloc(NNODES * 4);
    int*   cell      = (int*)alloc((size_t)NSCAN * 4);
    int*   ssum      = (int*)alloc(512 * 4);
    unsigned int*  tmp1 = (unsigned int*)alloc((size_t)NEDGES * 4);
    unsigned char* tmp2 = (unsigned char*)alloc((size_t)NEDGES);
    int*   row_ptr   = (int*)alloc((NNODES + 16) * 4);
    int*   csr_src   = (int*)alloc(NEDGES * 4);
    unsigned short* h   = (unsigned short*)alloc((size_t)MPAD * FH * 2);
    unsigned short* h1  = (unsigned short*)alloc((size_t)MPAD * FH * 2);
    unsigned short* Wt1 = (unsigned short*)alloc((size_t)FH * KDIM * 2);
    unsigned short* Wt2 = (unsigned short*)alloc((size_t)FOUT * KDIM * 2);
    unsigned short* h2  = h;

    l1_count_cast<<<NB1 + 96, 256, 0, stream>>>(src, dst, cell, W1, Wt1, W2, Wt2);
    scanA<<<SCANB, 512, 0, stream>>>(cell, ssum, NSCAN);
    scanB<<<1, 512, 0, stream>>>(ssum, SCANB);
    scanC<<<SCANB, 512, 0, stream>>>(cell, ssum, NSCAN);
    l1_scatter<<<NB1, 256, 0, stream>>>(src, dst, cell, tmp1, tmp2);
    l2_both<<<2 * NBUCK, 256, 0, stream>>>(tmp1, tmp2, cell, row_ptr, norm_dst, norm_src, csr_src);

    // layer 1: h = bf16((x*norm_src) @ W1) — single pass over A (NT=2 covers N=256)
    gemm_mfma<float, true, 2><<<dim3(MPAD / 128, 1), 256, 0, stream>>>(x, Wt1, norm_src, h, FH);
    agg1_kernel<<<MPAD / 4, 256, 0, stream>>>(h, row_ptr, csr_src, norm_dst, norm_src, b1, h1);

    // layer 2
    gemm_mfma<unsigned short, false, 1><<<dim3(MPAD / 128, 1), 256, 0, stream>>>(h1, Wt2, nullptr, h2, FOUT);
    agg2_kernel<<<(NNODES + 7) / 8, 256, 0, stream>>>(h2, row_ptr, csr_src, norm_dst, b2, out);
}

// Round 3
// 283.039 us; speedup vs baseline: 1.0130x; 1.0130x over previous
//
#include <hip/hip_runtime.h>

#define NNODES 50000
#define MPAD   50048    // padded to multiple of 128 for MFMA tiles
#define NEDGES 800000
#define KDIM   256      // in/hidden feature dim (GEMM K)
#define FH     256      // hidden feats
#define FOUT   128      // out feats

// ---- counting-sort geometry ----
#define SHIFT  8
#define NBUCK  196              // ceil(50000/256); max dst>>8 = 195
#define NB1    200              // level-1 blocks
#define EPB    4000             // edges per level-1 block (NB1*EPB == NEDGES)
#define CELLS  (NBUCK * NB1)    // 39200 per side
#define NSCAN  (2 * CELLS)      // 78400 (dst cells | src cells)
#define SCANB  ((NSCAN + 511) / 512)   // 154

typedef __bf16 bf16x8 __attribute__((ext_vector_type(8)));
typedef float floatx4 __attribute__((ext_vector_type(4)));

// ---------------- bf16 helpers (RNE) ----------------
__device__ __forceinline__ float bf2f(unsigned short u) {
    union { unsigned int i; float f; } v;
    v.i = ((unsigned int)u) << 16;
    return v.f;
}
__device__ __forceinline__ unsigned short f2bf(float f) {
    union { float f; unsigned int i; } v;
    v.f = f;
    unsigned int r = v.i + 0x7FFFu + ((v.i >> 16) & 1u);
    return (unsigned short)(r >> 16);
}

// ---------------- fused: level-1 histograms (blocks 0..NB1-1) + W transpose/cast (NB1..NB1+95)
__global__ __launch_bounds__(256) void l1_count_cast(const int* __restrict__ src,
                                                     const int* __restrict__ dst,
                                                     int* __restrict__ cell,
                                                     const float* __restrict__ W1,
                                                     unsigned short* __restrict__ Wt1,
                                                     const float* __restrict__ W2,
                                                     unsigned short* __restrict__ Wt2) {
    __shared__ int histD[256], histS[256];
    __shared__ float tile[32][33];
    const int tid = threadIdx.x;

    if (blockIdx.x >= NB1) {
        // ---- W1,W2 [K][N] -> Wt [N][K] bf16, LDS 32x32 transpose ----
        int b = blockIdx.x - NB1;
        const float* W; unsigned short* Wt; int N;
        if (b < 64) { W = W1; Wt = Wt1; N = FH; }
        else        { b -= 64; W = W2; Wt = Wt2; N = FOUT; }
        int kt = (b & 7) * 32;
        int nt = (b >> 3) * 32;
        int tx = tid & 31;
        int ty = tid >> 5;
        for (int r = ty; r < 32; r += 8)
            tile[r][tx] = W[(size_t)(kt + r) * N + nt + tx];
        __syncthreads();
        for (int r = ty; r < 32; r += 8)
            Wt[(size_t)(nt + r) * KDIM + kt + tx] = f2bf(tile[tx][r]);
        return;
    }

    const int b = blockIdx.x;
    const int base = b * EPB;
    histD[tid] = 0; histS[tid] = 0;
    __syncthreads();
    for (int g = tid; g < EPB / 4; g += 256) {
        uint4 s4 = *(const uint4*)(src + base + g * 4);
        uint4 d4 = *(const uint4*)(dst + base + g * 4);
        atomicAdd(&histD[d4.x >> SHIFT], 1);
        atomicAdd(&histD[d4.y >> SHIFT], 1);
        atomicAdd(&histD[d4.z >> SHIFT], 1);
        atomicAdd(&histD[d4.w >> SHIFT], 1);
        atomicAdd(&histS[s4.x >> SHIFT], 1);
        atomicAdd(&histS[s4.y >> SHIFT], 1);
        atomicAdd(&histS[s4.z >> SHIFT], 1);
        atomicAdd(&histS[s4.w >> SHIFT], 1);
    }
    __syncthreads();
    if (tid < NBUCK) {
        cell[tid * NB1 + b] = histD[tid];
        cell[CELLS + tid * NB1 + b] = histS[tid];
    }
}

// ---------------- generic 3-kernel exclusive scan ----------------
__global__ __launch_bounds__(512) void scanA(int* __restrict__ data,
                                             int* __restrict__ sums, int n) {
    __shared__ int s[512];
    int tid = threadIdx.x;
    int i = blockIdx.x * 512 + tid;
    int v = (i < n) ? data[i] : 0;
    s[tid] = v;
    __syncthreads();
    for (int off = 1; off < 512; off <<= 1) {
        int t = (tid >= off) ? s[tid - off] : 0;
        __syncthreads();
        s[tid] += t;
        __syncthreads();
    }
    if (i < n) data[i] = s[tid] - v;
    if (tid == 511) sums[blockIdx.x] = s[511];
}

__global__ __launch_bounds__(512) void scanB(int* __restrict__ sums, int nb) {
    __shared__ int s[512];
    int tid = threadIdx.x;
    int v = (tid < nb) ? sums[tid] : 0;
    s[tid] = v;
    __syncthreads();
    for (int off = 1; off < 512; off <<= 1) {
        int t = (tid >= off) ? s[tid - off] : 0;
        __syncthreads();
        s[tid] += t;
        __syncthreads();
    }
    if (tid < nb) sums[tid] = s[tid] - v;
}

__global__ __launch_bounds__(512) void scanC(int* __restrict__ data,
                                             const int* __restrict__ sums, int n) {
    int i = blockIdx.x * 512 + threadIdx.x;
    if (i < n) data[i] += sums[blockIdx.x];
}

// ---------------- level-1 scatter: in-block counting sort, coalesced global writes --------
__global__ __launch_bounds__(256) void l1_scatter(const int* __restrict__ src,
                                                  const int* __restrict__ dst,
                                                  const int* __restrict__ cell,  // scanned
                                                  unsigned int* __restrict__ tmp1,
                                                  unsigned char* __restrict__ tmp2) {
    __shared__ int histD[256], histS[256];
    __shared__ int exD[256], exS[256];
    __shared__ unsigned int bufD[EPB];
    __shared__ unsigned short bufS[EPB];
    const int b = blockIdx.x, tid = threadIdx.x;
    const int base = b * EPB;

    histD[tid] = 0; histS[tid] = 0;
    __syncthreads();
    for (int g = tid; g < EPB / 4; g += 256) {
        uint4 s4 = *(const uint4*)(src + base + g * 4);
        uint4 d4 = *(const uint4*)(dst + base + g * 4);
        atomicAdd(&histD[d4.x >> SHIFT], 1);
        atomicAdd(&histD[d4.y >> SHIFT], 1);
        atomicAdd(&histD[d4.z >> SHIFT], 1);
        atomicAdd(&histD[d4.w >> SHIFT], 1);
        atomicAdd(&histS[s4.x >> SHIFT], 1);
        atomicAdd(&histS[s4.y >> SHIFT], 1);
        atomicAdd(&histS[s4.z >> SHIFT], 1);
        atomicAdd(&histS[s4.w >> SHIFT], 1);
    }
    __syncthreads();
    int vD = histD[tid], vS = histS[tid];
    exD[tid] = vD; exS[tid] = vS;
    __syncthreads();
    for (int off = 1; off < 256; off <<= 1) {
        int tD = (tid >= off) ? exD[tid - off] : 0;
        int tS = (tid >= off) ? exS[tid - off] : 0;
        __syncthreads();
        exD[tid] += tD; exS[tid] += tS;
        __syncthreads();
    }
    int eD = exD[tid] - vD, eS = exS[tid] - vS;
    __syncthreads();
    exD[tid] = eD; exS[tid] = eS;
    histD[tid] = eD; histS[tid] = eS;
    __syncthreads();
    for (int g = tid; g < EPB / 4; g += 256) {
        uint4 s4 = *(const uint4*)(src + base + g * 4);
        uint4 d4 = *(const uint4*)(dst + base + g * 4);
        unsigned int ss[4] = {s4.x, s4.y, s4.z, s4.w};
        unsigned int dd[4] = {d4.x, d4.y, d4.z, d4.w};
#pragma unroll
        for (int j = 0; j < 4; ++j) {
            int p = atomicAdd(&histD[dd[j] >> SHIFT], 1);
            bufD[p] = (ss[j] << 16) | dd[j];
            int q = atomicAdd(&histS[ss[j] >> SHIFT], 1);
            bufS[q] = (unsigned short)ss[j];
        }
    }
    __syncthreads();
    for (int e = tid; e < EPB; e += 256) {
        unsigned int p = bufD[e];
        int k = (p & 0xFFFFu) >> SHIFT;
        tmp1[cell[k * NB1 + b] + (e - exD[k])] = p;
    }
    for (int e = tid; e < EPB; e += 256) {
        unsigned int s = bufS[e];
        int k = s >> SHIFT;
        tmp2[(cell[CELLS + k * NB1 + b] - NEDGES) + (e - exS[k])] = (unsigned char)(s & 255u);
    }
}

// ---------------- fused level-2: dst (blocks 0..NBUCK-1) + src (NBUCK..2*NBUCK-1) ---------
__global__ __launch_bounds__(256) void l2_both(const unsigned int* __restrict__ tmp1,
                                               const unsigned char* __restrict__ tmp2,
                                               const int* __restrict__ cell,
                                               int* __restrict__ row_ptr,
                                               float* __restrict__ norm_dst,
                                               float* __restrict__ norm_src,
                                               int* __restrict__ csr_src) {
    __shared__ int cnt[256], ofs[256], cur[256];
    const int tid = threadIdx.x;

    if (blockIdx.x >= NBUCK) {
        // ---- src side: counts -> norm_src ----
        const int k = blockIdx.x - NBUCK;
        const int start = cell[CELLS + k * NB1] - NEDGES;
        const int end = (k + 1 < NBUCK) ? cell[CELLS + (k + 1) * NB1] - NEDGES : NEDGES;
        cnt[tid] = 0;
        __syncthreads();
        for (int e = start + tid; e < end; e += 256)
            atomicAdd(&cnt[tmp2[e]], 1);
        __syncthreads();
        int node = k * 256 + tid;
        if (node < NNODES) {
            int d = cnt[tid] < 1 ? 1 : cnt[tid];
            norm_src[node] = 1.0f / sqrtf((float)d);
        }
        return;
    }

    // ---- dst side: exact counts + row_ptr + norm_dst + csr scatter ----
    const int k = blockIdx.x;
    const int start = cell[k * NB1];
    const int end = (k + 1 < NBUCK) ? cell[(k + 1) * NB1] : NEDGES;
    cnt[tid] = 0;
    __syncthreads();
    for (int e = start + tid; e < end; e += 256)
        atomicAdd(&cnt[tmp1[e] & 255u], 1);
    __syncthreads();
    int v = cnt[tid];
    ofs[tid] = v;
    __syncthreads();
    for (int off = 1; off < 256; off <<= 1) {
        int t = (tid >= off) ? ofs[tid - off] : 0;
        __syncthreads();
        ofs[tid] += t;
        __syncthreads();
    }
    int excl = ofs[tid] - v;
    int node = k * 256 + tid;
    if (node < NNODES) {
        row_ptr[node] = start + excl;
        int d = v < 1 ? 1 : v;
        norm_dst[node] = 1.0f / sqrtf((float)d);
    }
    cur[tid] = start + excl;
    if (k == 0 && tid == 0) row_ptr[NNODES] = NEDGES;
    __syncthreads();
    for (int e = start + tid; e < end; e += 256) {
        unsigned int p = tmp1[e];
        int pos = atomicAdd(&cur[p & 255u], 1);
        csr_src[pos] = (int)(p >> 16);
    }
}

// ---------------- raw A loaders: keep global loads separate from bf16 pack so the
// s_waitcnt lands at the LDS-write site (full-iteration prefetch distance) ----------------
template <typename TA> struct araw_t;
template <> struct araw_t<float> { float4 v0, v1; };
template <> struct araw_t<unsigned short> { uint4 v; };

__device__ __forceinline__ void load_a_raw(const float* A, int row, int k, araw_t<float>& r) {
    const float* p = A + (size_t)row * KDIM + k;
    r.v0 = *(const float4*)p;
    r.v1 = *(const float4*)(p + 4);
}
__device__ __forceinline__ void load_a_raw(const unsigned short* A, int row, int k, araw_t<unsigned short>& r) {
    r.v = *(const uint4*)(A + (size_t)row * KDIM + k);
}
__device__ __forceinline__ uint4 pack_a(const araw_t<float>& r, float scale) {
    union { uint4 u; unsigned short s[8]; } o;
    o.s[0] = f2bf(r.v0.x * scale); o.s[1] = f2bf(r.v0.y * scale);
    o.s[2] = f2bf(r.v0.z * scale); o.s[3] = f2bf(r.v0.w * scale);
    o.s[4] = f2bf(r.v1.x * scale); o.s[5] = f2bf(r.v1.y * scale);
    o.s[6] = f2bf(r.v1.z * scale); o.s[7] = f2bf(r.v1.w * scale);
    return o.u;
}
__device__ __forceinline__ uint4 pack_a(const araw_t<unsigned short>& r, float) { return r.v; }

// ---------------- bf16 MFMA GEMM: C[M, BN] = (A[M,256] * norm?) @ Bt[BN,256]^T ------------
// BM=64 rows/block -> 782 blocks (~3/CU, 12 waves/CU). Double-buffered LDS (pad 40),
// register prefetch 1 K-step ahead, ONE barrier per K-step. Single pass over A.
template <typename TA, bool SCALE, int BN>
__global__ __launch_bounds__(256) void gemm_mfma(const TA* __restrict__ A,
                                                 const unsigned short* __restrict__ Bt,
                                                 const float* __restrict__ norm,
                                                 unsigned short* __restrict__ C,
                                                 int N) {
    constexpr int NB = BN / 64;   // B rows staged per thread per K-step; also j-frags per wave
    __shared__ __align__(16) unsigned short As[2][64][40];
    __shared__ __align__(16) unsigned short Bs[2][BN][40];

    const int tid = threadIdx.x;
    const int lane = tid & 63;
    const int wave = tid >> 6;
    const int m0 = blockIdx.x * 64;
    const int srow = tid >> 2;           // 0..63
    const int sk = (tid & 3) << 3;       // 0,8,16,24

    const int r0 = m0 + srow;
    bool va0 = true;
    float sc0 = 1.f;
    if (SCALE) { va0 = (r0 < NNODES); sc0 = va0 ? norm[r0] : 0.f; }
    const int ra = (SCALE && !va0) ? 0 : r0;

    const unsigned short* Bg = Bt + (size_t)srow * KDIM + sk;

    araw_t<TA> a;
    uint4 b[NB];

    // K-step 0 loads -> buf 0
    load_a_raw(A, ra, sk, a);
#pragma unroll
    for (int t = 0; t < NB; ++t) b[t] = *(const uint4*)(Bg + (size_t)(64 * t) * KDIM);
    *(uint4*)&As[0][srow][sk] = pack_a(a, sc0);
#pragma unroll
    for (int t = 0; t < NB; ++t) *(uint4*)&Bs[0][srow + 64 * t][sk] = b[t];

    // K-step 1 loads (in flight across first MFMA block)
    load_a_raw(A, ra, 32 + sk, a);
#pragma unroll
    for (int t = 0; t < NB; ++t) b[t] = *(const uint4*)(Bg + (size_t)(64 * t) * KDIM + 32);

    floatx4 acc[4][NB] = {};
    const int ar = lane & 15;
    const int fk = (lane >> 4) << 3;
    const int wb = wave * (BN / 4);

#pragma unroll
    for (int kk = 0; kk < 8; ++kk) {
        __syncthreads();
        const int cur = kk & 1;
        bf16x8 af[4], bfr[NB];
#pragma unroll
        for (int i = 0; i < 4; ++i)
            af[i] = *(const bf16x8*)&As[cur][ar + i * 16][fk];
#pragma unroll
        for (int j = 0; j < NB; ++j)
            bfr[j] = *(const bf16x8*)&Bs[cur][wb + ar + j * 16][fk];
#pragma unroll
        for (int i = 0; i < 4; ++i)
#pragma unroll
            for (int j = 0; j < NB; ++j)
                acc[i][j] = __builtin_amdgcn_mfma_f32_16x16x32_bf16(af[i], bfr[j], acc[i][j], 0, 0, 0);
        if (kk < 7) {
            const int nxt = cur ^ 1;
            *(uint4*)&As[nxt][srow][sk] = pack_a(a, sc0);
#pragma unroll
            for (int t = 0; t < NB; ++t) *(uint4*)&Bs[nxt][srow + 64 * t][sk] = b[t];
            if (kk < 6) {
                load_a_raw(A, ra, (kk + 2) * 32 + sk, a);
#pragma unroll
                for (int t = 0; t < NB; ++t)
                    b[t] = *(const uint4*)(Bg + (size_t)(64 * t) * KDIM + (kk + 2) * 32);
            }
        }
    }

    const int rb = (lane >> 4) << 2;
    const int cc = lane & 15;
#pragma unroll
    for (int i = 0; i < 4; ++i) {
        int mb = m0 + i * 16 + rb;
#pragma unroll
        for (int j = 0; j < NB; ++j) {
            int col = wb + j * 16 + cc;
#pragma unroll
            for (int r = 0; r < 4; ++r) {
                int m = mb + r;
                if (m < NNODES)
                    C[(size_t)m * N + col] = f2bf(acc[i][j][r]);
            }
        }
    }
}

// ---------------- agg layer 1: bf16 in (F=256), bf16 out. Full row per wave,
// 8-deep + 4-deep + scalar unroll. h1 = relu(agg*norm_dst+b1)*norm_src; pad rows zero.
__global__ __launch_bounds__(256) void agg1_kernel(const unsigned short* __restrict__ H,
                                                   const int* __restrict__ row_ptr,
                                                   const int* __restrict__ csr_src,
                                                   const float* __restrict__ norm_dst,
                                                   const float* __restrict__ norm_src,
                                                   const float* __restrict__ bias,
                                                   unsigned short* __restrict__ out) {
    const int F = 256;
    int node = blockIdx.x * 4 + (threadIdx.x >> 6);
    int lane = threadIdx.x & 63;
    int f0 = lane * 4;
    if (node >= NNODES) {
        if (node < MPAD) {
            ushort4 z = {0, 0, 0, 0};
            *(ushort4*)(out + (size_t)node * F + f0) = z;
        }
        return;
    }
    int e0 = row_ptr[node];
    int e1 = row_ptr[node + 1];

    float acc0 = 0.f, acc1 = 0.f, acc2 = 0.f, acc3 = 0.f;
    const unsigned short* Hl = H + f0;

    int e = e0;
    for (; e + 7 < e1; e += 8) {
        ushort4 v[8];
#pragma unroll
        for (int u = 0; u < 8; ++u)
            v[u] = *(const ushort4*)(Hl + (size_t)csr_src[e + u] * F);
#pragma unroll
        for (int u = 0; u < 8; ++u) {
            acc0 += bf2f(v[u].x); acc1 += bf2f(v[u].y);
            acc2 += bf2f(v[u].z); acc3 += bf2f(v[u].w);
        }
    }
    for (; e + 3 < e1; e += 4) {
        ushort4 v[4];
#pragma unroll
        for (int u = 0; u < 4; ++u)
            v[u] = *(const ushort4*)(Hl + (size_t)csr_src[e + u] * F);
#pragma unroll
        for (int u = 0; u < 4; ++u) {
            acc0 += bf2f(v[u].x); acc1 += bf2f(v[u].y);
            acc2 += bf2f(v[u].z); acc3 += bf2f(v[u].w);
        }
    }
    for (; e < e1; ++e) {
        ushort4 v = *(const ushort4*)(Hl + (size_t)csr_src[e] * F);
        acc0 += bf2f(v.x); acc1 += bf2f(v.y); acc2 += bf2f(v.z); acc3 += bf2f(v.w);
    }

    float nd = norm_dst[node];
    float ns = norm_src[node];
    float o0 = fmaxf(fmaf(acc0, nd, bias[f0 + 0]), 0.0f) * ns;
    float o1 = fmaxf(fmaf(acc1, nd, bias[f0 + 1]), 0.0f) * ns;
    float o2 = fmaxf(fmaf(acc2, nd, bias[f0 + 2]), 0.0f) * ns;
    float o3 = fmaxf(fmaf(acc3, nd, bias[f0 + 3]), 0.0f) * ns;
    ushort4 o;
    o.x = f2bf(o0); o.y = f2bf(o1); o.z = f2bf(o2); o.w = f2bf(o3);
    *(ushort4*)(out + (size_t)node * F + f0) = o;
}

// ---------------- agg layer 2: bf16 in (F=128), fp32 out, no relu. Half-wave per node. ----
__global__ __launch_bounds__(256) void agg2_kernel(const unsigned short* __restrict__ H,
                                                   const int* __restrict__ row_ptr,
                                                   const int* __restrict__ csr_src,
                                                   const float* __restrict__ norm_dst,
                                                   const float* __restrict__ bias,
                                                   float* __restrict__ out) {
    const int F = 128;
    int node = blockIdx.x * 8 + (threadIdx.x >> 5);
    if (node >= NNODES) return;
    int lane = threadIdx.x & 31;
    int f0 = lane * 4;
    int e0 = row_ptr[node];
    int e1 = row_ptr[node + 1];

    float acc0 = 0.f, acc1 = 0.f, acc2 = 0.f, acc3 = 0.f;
    const unsigned short* Hl = H + f0;

    int e = e0;
    for (; e + 7 < e1; e += 8) {
        ushort4 v[8];
#pragma unroll
        for (int u = 0; u < 8; ++u)
            v[u] = *(const ushort4*)(Hl + (size_t)csr_src[e + u] * F);
#pragma unroll
        for (int u = 0; u < 8; ++u) {
            acc0 += bf2f(v[u].x); acc1 += bf2f(v[u].y);
            acc2 += bf2f(v[u].z); acc3 += bf2f(v[u].w);
        }
    }
    for (; e + 3 < e1; e += 4) {
        ushort4 v[4];
#pragma unroll
        for (int u = 0; u < 4; ++u)
            v[u] = *(const ushort4*)(Hl + (size_t)csr_src[e + u] * F);
#pragma unroll
        for (int u = 0; u < 4; ++u) {
            acc0 += bf2f(v[u].x); acc1 += bf2f(v[u].y);
            acc2 += bf2f(v[u].z); acc3 += bf2f(v[u].w);
        }
    }
    for (; e < e1; ++e) {
        ushort4 v = *(const ushort4*)(Hl + (size_t)csr_src[e] * F);
        acc0 += bf2f(v.x); acc1 += bf2f(v.y); acc2 += bf2f(v.z); acc3 += bf2f(v.w);
    }

    float nd = norm_dst[node];
    float4 o;
    o.x = fmaf(acc0, nd, bias[f0 + 0]);
    o.y = fmaf(acc1, nd, bias[f0 + 1]);
    o.z = fmaf(acc2, nd, bias[f0 + 2]);
    o.w = fmaf(acc3, nd, bias[f0 + 3]);
    *(float4*)(out + (size_t)node * F + f0) = o;
}

// ---------------- launch ----------------
extern "C" void kernel_launch(void* const* d_in, const int* in_sizes, int n_in,
                              void* d_out, int out_size, void* d_ws, size_t ws_size,
                              hipStream_t stream) {
    const float* x   = (const float*)d_in[0];
    const int*   src = (const int*)d_in[1];
    const int*   dst = (const int*)d_in[2];
    const float* W1  = (const float*)d_in[3];
    const float* b1  = (const float*)d_in[4];
    const float* W2  = (const float*)d_in[5];
    const float* b2  = (const float*)d_in[6];
    float* out = (float*)d_out;

    char* ws = (char*)d_ws;
    size_t off = 0;
    auto alloc = [&](size_t bytes) {
        char* p = ws + off;
        off += (bytes + 255) & ~(size_t)255;
        return p;
    };
    float* norm_src  = (float*)alloc(NNODES * 4);
    float* norm_dst  = (float*)alloc(NNODES * 4);
    int*   cell      = (int*)alloc((size_t)NSCAN * 4);
    int*   ssum      = (int*)alloc(512 * 4);
    unsigned int*  tmp1 = (unsigned int*)alloc((size_t)NEDGES * 4);
    unsigned char* tmp2 = (unsigned char*)alloc((size_t)NEDGES);
    int*   row_ptr   = (int*)alloc((NNODES + 16) * 4);
    int*   csr_src   = (int*)alloc(NEDGES * 4);
    unsigned short* h   = (unsigned short*)alloc((size_t)MPAD * FH * 2);
    unsigned short* h1  = (unsigned short*)alloc((size_t)MPAD * FH * 2);
    unsigned short* Wt1 = (unsigned short*)alloc((size_t)FH * KDIM * 2);
    unsigned short* Wt2 = (unsigned short*)alloc((size_t)FOUT * KDIM * 2);
    unsigned short* h2  = h;

    l1_count_cast<<<NB1 + 96, 256, 0, stream>>>(src, dst, cell, W1, Wt1, W2, Wt2);
    scanA<<<SCANB, 512, 0, stream>>>(cell, ssum, NSCAN);
    scanB<<<1, 512, 0, stream>>>(ssum, SCANB);
    scanC<<<SCANB, 512, 0, stream>>>(cell, ssum, NSCAN);
    l1_scatter<<<NB1, 256, 0, stream>>>(src, dst, cell, tmp1, tmp2);
    l2_both<<<2 * NBUCK, 256, 0, stream>>>(tmp1, tmp2, cell, row_ptr, norm_dst, norm_src, csr_src);

    // layer 1: h = bf16((x*norm_src) @ W1) — BM=64, BN=256, single pass over x
    gemm_mfma<float, true, 256><<<MPAD / 64, 256, 0, stream>>>(x, Wt1, norm_src, h, FH);
    agg1_kernel<<<MPAD / 4, 256, 0, stream>>>(h, row_ptr, csr_src, norm_dst, norm_src, b1, h1);

    // layer 2 — BM=64, BN=128
    gemm_mfma<unsigned short, false, 128><<<MPAD / 64, 256, 0, stream>>>(h1, Wt2, nullptr, h2, FOUT);
    agg2_kernel<<<(NNODES + 7) / 8, 256, 0, stream>>>(h2, row_ptr, csr_src, norm_dst, b2, out);
}

// Round 4
// 268.467 us; speedup vs baseline: 1.0680x; 1.0543x over previous
//
#include <hip/hip_runtime.h>

#define NNODES 50000
#define MPAD   50048    // padded to multiple of 64 for MFMA tiles
#define NEDGES 800000
#define KDIM   256      // in/hidden feature dim (GEMM K)
#define FH     256      // hidden feats
#define FOUT   128      // out feats

// ---- counting-sort geometry ----
#define SHIFT  8
#define NBUCK  196              // ceil(50000/256); max dst>>8 = 195
#define NB1    200              // level-1 blocks
#define EPB    4000             // edges per level-1 block (NB1*EPB == NEDGES)
#define CELLS  (NBUCK * NB1)    // 39200 per side
#define NSCAN  (2 * CELLS)      // 78400 (dst cells | src cells)
#define SCANB  ((NSCAN + 511) / 512)   // 154

typedef __bf16 bf16x8 __attribute__((ext_vector_type(8)));
typedef float floatx4 __attribute__((ext_vector_type(4)));

// ---------------- bf16 helpers (RNE) ----------------
__device__ __forceinline__ float bf2f(unsigned short u) {
    union { unsigned int i; float f; } v;
    v.i = ((unsigned int)u) << 16;
    return v.f;
}
__device__ __forceinline__ unsigned short f2bf(float f) {
    union { float f; unsigned int i; } v;
    v.f = f;
    unsigned int r = v.i + 0x7FFFu + ((v.i >> 16) & 1u);
    return (unsigned short)(r >> 16);
}

// ---------------- fused: level-1 histograms (blocks 0..NB1-1) + W transpose/cast (NB1..NB1+95)
__global__ __launch_bounds__(256) void l1_count_cast(const int* __restrict__ src,
                                                     const int* __restrict__ dst,
                                                     int* __restrict__ cell,
                                                     const float* __restrict__ W1,
                                                     unsigned short* __restrict__ Wt1,
                                                     const float* __restrict__ W2,
                                                     unsigned short* __restrict__ Wt2) {
    __shared__ int histD[256], histS[256];
    __shared__ float tile[32][33];
    const int tid = threadIdx.x;

    if (blockIdx.x >= NB1) {
        // ---- W1,W2 [K][N] -> Wt [N][K] bf16, LDS 32x32 transpose ----
        int b = blockIdx.x - NB1;
        const float* W; unsigned short* Wt; int N;
        if (b < 64) { W = W1; Wt = Wt1; N = FH; }
        else        { b -= 64; W = W2; Wt = Wt2; N = FOUT; }
        int kt = (b & 7) * 32;
        int nt = (b >> 3) * 32;
        int tx = tid & 31;
        int ty = tid >> 5;
        for (int r = ty; r < 32; r += 8)
            tile[r][tx] = W[(size_t)(kt + r) * N + nt + tx];
        __syncthreads();
        for (int r = ty; r < 32; r += 8)
            Wt[(size_t)(nt + r) * KDIM + kt + tx] = f2bf(tile[tx][r]);
        return;
    }

    const int b = blockIdx.x;
    const int base = b * EPB;
    histD[tid] = 0; histS[tid] = 0;
    __syncthreads();
    for (int g = tid; g < EPB / 4; g += 256) {
        uint4 s4 = *(const uint4*)(src + base + g * 4);
        uint4 d4 = *(const uint4*)(dst + base + g * 4);
        atomicAdd(&histD[d4.x >> SHIFT], 1);
        atomicAdd(&histD[d4.y >> SHIFT], 1);
        atomicAdd(&histD[d4.z >> SHIFT], 1);
        atomicAdd(&histD[d4.w >> SHIFT], 1);
        atomicAdd(&histS[s4.x >> SHIFT], 1);
        atomicAdd(&histS[s4.y >> SHIFT], 1);
        atomicAdd(&histS[s4.z >> SHIFT], 1);
        atomicAdd(&histS[s4.w >> SHIFT], 1);
    }
    __syncthreads();
    if (tid < NBUCK) {
        cell[tid * NB1 + b] = histD[tid];
        cell[CELLS + tid * NB1 + b] = histS[tid];
    }
}

// ---------------- generic 3-kernel exclusive scan ----------------
__global__ __launch_bounds__(512) void scanA(int* __restrict__ data,
                                             int* __restrict__ sums, int n) {
    __shared__ int s[512];
    int tid = threadIdx.x;
    int i = blockIdx.x * 512 + tid;
    int v = (i < n) ? data[i] : 0;
    s[tid] = v;
    __syncthreads();
    for (int off = 1; off < 512; off <<= 1) {
        int t = (tid >= off) ? s[tid - off] : 0;
        __syncthreads();
        s[tid] += t;
        __syncthreads();
    }
    if (i < n) data[i] = s[tid] - v;
    if (tid == 511) sums[blockIdx.x] = s[511];
}

__global__ __launch_bounds__(512) void scanB(int* __restrict__ sums, int nb) {
    __shared__ int s[512];
    int tid = threadIdx.x;
    int v = (tid < nb) ? sums[tid] : 0;
    s[tid] = v;
    __syncthreads();
    for (int off = 1; off < 512; off <<= 1) {
        int t = (tid >= off) ? s[tid - off] : 0;
        __syncthreads();
        s[tid] += t;
        __syncthreads();
    }
    if (tid < nb) sums[tid] = s[tid] - v;
}

__global__ __launch_bounds__(512) void scanC(int* __restrict__ data,
                                             const int* __restrict__ sums, int n) {
    int i = blockIdx.x * 512 + threadIdx.x;
    if (i < n) data[i] += sums[blockIdx.x];
}

// ---------------- level-1 scatter: in-block counting sort, coalesced global writes --------
__global__ __launch_bounds__(256) void l1_scatter(const int* __restrict__ src,
                                                  const int* __restrict__ dst,
                                                  const int* __restrict__ cell,  // scanned
                                                  unsigned int* __restrict__ tmp1,
                                                  unsigned char* __restrict__ tmp2) {
    __shared__ int histD[256], histS[256];
    __shared__ int exD[256], exS[256];
    __shared__ unsigned int bufD[EPB];
    __shared__ unsigned short bufS[EPB];
    const int b = blockIdx.x, tid = threadIdx.x;
    const int base = b * EPB;

    histD[tid] = 0; histS[tid] = 0;
    __syncthreads();
    for (int g = tid; g < EPB / 4; g += 256) {
        uint4 s4 = *(const uint4*)(src + base + g * 4);
        uint4 d4 = *(const uint4*)(dst + base + g * 4);
        atomicAdd(&histD[d4.x >> SHIFT], 1);
        atomicAdd(&histD[d4.y >> SHIFT], 1);
        atomicAdd(&histD[d4.z >> SHIFT], 1);
        atomicAdd(&histD[d4.w >> SHIFT], 1);
        atomicAdd(&histS[s4.x >> SHIFT], 1);
        atomicAdd(&histS[s4.y >> SHIFT], 1);
        atomicAdd(&histS[s4.z >> SHIFT], 1);
        atomicAdd(&histS[s4.w >> SHIFT], 1);
    }
    __syncthreads();
    int vD = histD[tid], vS = histS[tid];
    exD[tid] = vD; exS[tid] = vS;
    __syncthreads();
    for (int off = 1; off < 256; off <<= 1) {
        int tD = (tid >= off) ? exD[tid - off] : 0;
        int tS = (tid >= off) ? exS[tid - off] : 0;
        __syncthreads();
        exD[tid] += tD; exS[tid] += tS;
        __syncthreads();
    }
    int eD = exD[tid] - vD, eS = exS[tid] - vS;
    __syncthreads();
    exD[tid] = eD; exS[tid] = eS;
    histD[tid] = eD; histS[tid] = eS;
    __syncthreads();
    for (int g = tid; g < EPB / 4; g += 256) {
        uint4 s4 = *(const uint4*)(src + base + g * 4);
        uint4 d4 = *(const uint4*)(dst + base + g * 4);
        unsigned int ss[4] = {s4.x, s4.y, s4.z, s4.w};
        unsigned int dd[4] = {d4.x, d4.y, d4.z, d4.w};
#pragma unroll
        for (int j = 0; j < 4; ++j) {
            int p = atomicAdd(&histD[dd[j] >> SHIFT], 1);
            bufD[p] = (ss[j] << 16) | dd[j];
            int q = atomicAdd(&histS[ss[j] >> SHIFT], 1);
            bufS[q] = (unsigned short)ss[j];
        }
    }
    __syncthreads();
    for (int e = tid; e < EPB; e += 256) {
        unsigned int p = bufD[e];
        int k = (p & 0xFFFFu) >> SHIFT;
        tmp1[cell[k * NB1 + b] + (e - exD[k])] = p;
    }
    for (int e = tid; e < EPB; e += 256) {
        unsigned int s = bufS[e];
        int k = s >> SHIFT;
        tmp2[(cell[CELLS + k * NB1 + b] - NEDGES) + (e - exS[k])] = (unsigned char)(s & 255u);
    }
}

// ---------------- fused level-2: dst (blocks 0..NBUCK-1) + src (NBUCK..2*NBUCK-1) ---------
__global__ __launch_bounds__(256) void l2_both(const unsigned int* __restrict__ tmp1,
                                               const unsigned char* __restrict__ tmp2,
                                               const int* __restrict__ cell,
                                               int* __restrict__ row_ptr,
                                               float* __restrict__ norm_dst,
                                               float* __restrict__ norm_src,
                                               int* __restrict__ csr_src) {
    __shared__ int cnt[256], ofs[256], cur[256];
    const int tid = threadIdx.x;

    if (blockIdx.x >= NBUCK) {
        // ---- src side: counts -> norm_src ----
        const int k = blockIdx.x - NBUCK;
        const int start = cell[CELLS + k * NB1] - NEDGES;
        const int end = (k + 1 < NBUCK) ? cell[CELLS + (k + 1) * NB1] - NEDGES : NEDGES;
        cnt[tid] = 0;
        __syncthreads();
        for (int e = start + tid; e < end; e += 256)
            atomicAdd(&cnt[tmp2[e]], 1);
        __syncthreads();
        int node = k * 256 + tid;
        if (node < NNODES) {
            int d = cnt[tid] < 1 ? 1 : cnt[tid];
            norm_src[node] = 1.0f / sqrtf((float)d);
        }
        return;
    }

    // ---- dst side: exact counts + row_ptr + norm_dst + csr scatter ----
    const int k = blockIdx.x;
    const int start = cell[k * NB1];
    const int end = (k + 1 < NBUCK) ? cell[(k + 1) * NB1] : NEDGES;
    cnt[tid] = 0;
    __syncthreads();
    for (int e = start + tid; e < end; e += 256)
        atomicAdd(&cnt[tmp1[e] & 255u], 1);
    __syncthreads();
    int v = cnt[tid];
    ofs[tid] = v;
    __syncthreads();
    for (int off = 1; off < 256; off <<= 1) {
        int t = (tid >= off) ? ofs[tid - off] : 0;
        __syncthreads();
        ofs[tid] += t;
        __syncthreads();
    }
    int excl = ofs[tid] - v;
    int node = k * 256 + tid;
    if (node < NNODES) {
        row_ptr[node] = start + excl;
        int d = v < 1 ? 1 : v;
        norm_dst[node] = 1.0f / sqrtf((float)d);
    }
    cur[tid] = start + excl;
    if (k == 0 && tid == 0) row_ptr[NNODES] = NEDGES;
    __syncthreads();
    for (int e = start + tid; e < end; e += 256) {
        unsigned int p = tmp1[e];
        int pos = atomicAdd(&cur[p & 255u], 1);
        csr_src[pos] = (int)(p >> 16);
    }
}

// ================= B-resident GEMM =================
// C[M, 128*NPANEL] = (A[M,256] * norm?) @ Bt[col][k]^T
// Whole 128-col B panel staged in LDS ONCE (64KB, XOR-swizzled). Then per 64-row A-tile:
// stage A (32KB LDS, swizzled), run the ENTIRE K=256 with zero barriers, store C.
// 2 barriers per M-tile (vs 2 per 32-K before) -> barrier-drain amortized 8x.
// 512 threads (8 waves: wn=wave&3 -> 32 cols, wm=wave>>2 -> 32-row half), 96KB LDS, 1 block/CU.

struct arawF { float4 v[8]; float sc; };
struct arawU { uint4 v[4]; };
template <typename TA> struct rawsel;
template <> struct rawsel<float> { using type = arawF; };
template <> struct rawsel<unsigned short> { using type = arawU; };

__device__ __forceinline__ void loadA_raw(const float* A, const float* norm,
                                          int mt, int arow, int akseg, arawF& r) {
    int row = mt * 64 + arow;
    if (row < NNODES) {
        const float* p = A + (size_t)row * KDIM + akseg;
#pragma unroll
        for (int j = 0; j < 8; ++j) r.v[j] = *(const float4*)(p + j * 4);
        r.sc = norm[row];
    } else {
        float4 z = {0.f, 0.f, 0.f, 0.f};
#pragma unroll
        for (int j = 0; j < 8; ++j) r.v[j] = z;
        r.sc = 0.f;
    }
}
__device__ __forceinline__ void loadA_raw(const unsigned short* A, const float*,
                                          int mt, int arow, int akseg, arawU& r) {
    const unsigned short* p = A + (size_t)(mt * 64 + arow) * KDIM + akseg;  // rows < MPAD, zero-padded
#pragma unroll
    for (int j = 0; j < 4; ++j) r.v[j] = *(const uint4*)(p + j * 8);
}
__device__ __forceinline__ void writeA_lds(char* Asb, int arow, int akseg, const arawF& r) {
    const int s = (arow & 7) << 4;
    const int base = arow * 512;
#pragma unroll
    for (int j = 0; j < 4; ++j) {
        union { uint4 u; unsigned short h[8]; } o;
        float4 a = r.v[2 * j], b = r.v[2 * j + 1];
        o.h[0] = f2bf(a.x * r.sc); o.h[1] = f2bf(a.y * r.sc);
        o.h[2] = f2bf(a.z * r.sc); o.h[3] = f2bf(a.w * r.sc);
        o.h[4] = f2bf(b.x * r.sc); o.h[5] = f2bf(b.y * r.sc);
        o.h[6] = f2bf(b.z * r.sc); o.h[7] = f2bf(b.w * r.sc);
        *(uint4*)(Asb + base + (((akseg + j * 8) * 2) ^ s)) = o.u;
    }
}
__device__ __forceinline__ void writeA_lds(char* Asb, int arow, int akseg, const arawU& r) {
    const int s = (arow & 7) << 4;
    const int base = arow * 512;
#pragma unroll
    for (int j = 0; j < 4; ++j)
        *(uint4*)(Asb + base + (((akseg + j * 8) * 2) ^ s)) = r.v[j];
}

template <typename TA, bool SCALE, int NPANEL>
__global__ __launch_bounds__(512) void gemm_bres(const TA* __restrict__ A,
                                                 const unsigned short* __restrict__ Bt,
                                                 const float* __restrict__ norm,
                                                 unsigned short* __restrict__ C) {
    constexpr int N = 128 * NPANEL;
    constexpr int NTILES = MPAD / 64;
    __shared__ __align__(16) unsigned short Bs[128 * 256];   // 64KB, [col][k] swizzled
    __shared__ __align__(16) unsigned short As[64 * 256];    // 32KB, [row][k] swizzled
    char* Bsb = (char*)Bs;
    char* Asb = (char*)As;

    const int tid = threadIdx.x;
    const int lane = tid & 63;
    const int wave = tid >> 6;

    // panel/tile mapping. NPANEL=2: pair panel-blocks 8 apart (same XCD via bid%8) so
    // both panels of the same M-range share x rows in that XCD's L2.
    int col0, mt0, mstep;
    if (NPANEL == 2) {
        col0 = ((blockIdx.x >> 3) & 1) * 128;
        mt0 = ((blockIdx.x >> 4) << 3) + (blockIdx.x & 7);
        mstep = gridDim.x >> 1;
    } else {
        col0 = 0;
        mt0 = blockIdx.x;
        mstep = gridDim.x;
    }

    // ---- stage B panel once: 512 threads x 128B ----
    {
        int col = tid >> 2;
        int kq = (tid & 3) * 64;
        const unsigned short* bg = Bt + (size_t)(col0 + col) * KDIM + kq;
        const int s = (col & 7) << 4;
        const int base = col * 512;
#pragma unroll
        for (int j = 0; j < 8; ++j) {
            uint4 v = *(const uint4*)(bg + j * 8);
            *(uint4*)(Bsb + base + (((kq + j * 8) * 2) ^ s)) = v;
        }
    }

    // ---- A staging geometry: thread -> (row, 32-k segment) ----
    const int arow = tid >> 3;           // 0..63
    const int akseg = (tid & 7) * 32;    // 0,32,...,224

    typename rawsel<TA>::type buf;
    loadA_raw(A, norm, mt0, arow, akseg, buf);
    writeA_lds(Asb, arow, akseg, buf);
    __syncthreads();                      // B + A(tile0) visible
    int mt = mt0, mtn = mt0 + mstep;
    if (mtn < NTILES) loadA_raw(A, norm, mtn, arow, akseg, buf);   // full MFMA phase to land

    // ---- per-wave fragment addressing ----
    const int wn = wave & 3, wm = wave >> 2;
    const int ar = lane & 15;
    const int fkb = (lane >> 4) << 4;    // 0,16,32,48 byte k-offset
    const int rA0 = wm * 32 + ar,  rA1 = rA0 + 16;
    const int cB0 = wn * 32 + ar,  cB1 = cB0 + 16;
    const int aO0 = rA0 * 512, aS0 = (rA0 & 7) << 4;
    const int aO1 = rA1 * 512, aS1 = (rA1 & 7) << 4;
    const int bO0 = cB0 * 512, bS0 = (cB0 & 7) << 4;
    const int bO1 = cB1 * 512, bS1 = (cB1 & 7) << 4;
    const int rb = (lane >> 4) << 2, cc = lane & 15;

    for (;;) {
        floatx4 a00 = {}, a01 = {}, a10 = {}, a11 = {};
#pragma unroll
        for (int kk = 0; kk < 8; ++kk) {
            const int kb = kk * 64 + fkb;
            bf16x8 fa0 = *(const bf16x8*)(Asb + aO0 + (kb ^ aS0));
            bf16x8 fa1 = *(const bf16x8*)(Asb + aO1 + (kb ^ aS1));
            bf16x8 fb0 = *(const bf16x8*)(Bsb + bO0 + (kb ^ bS0));
            bf16x8 fb1 = *(const bf16x8*)(Bsb + bO1 + (kb ^ bS1));
            a00 = __builtin_amdgcn_mfma_f32_16x16x32_bf16(fa0, fb0, a00, 0, 0, 0);
            a01 = __builtin_amdgcn_mfma_f32_16x16x32_bf16(fa0, fb1, a01, 0, 0, 0);
            a10 = __builtin_amdgcn_mfma_f32_16x16x32_bf16(fa1, fb0, a10, 0, 0, 0);
            a11 = __builtin_amdgcn_mfma_f32_16x16x32_bf16(fa1, fb1, a11, 0, 0, 0);
        }
        // ---- store C tile ----
        {
            const int mBase = mt * 64 + wm * 32 + rb;
            const int cBase = col0 + wn * 32 + cc;
#pragma unroll
            for (int r = 0; r < 4; ++r) {
                int m = mBase + r;
                if (m < NNODES) {
                    C[(size_t)m * N + cBase]      = f2bf(a00[r]);
                    C[(size_t)m * N + cBase + 16] = f2bf(a01[r]);
                }
                int m2 = m + 16;
                if (m2 < NNODES) {
                    C[(size_t)m2 * N + cBase]      = f2bf(a10[r]);
                    C[(size_t)m2 * N + cBase + 16] = f2bf(a11[r]);
                }
            }
        }
        if (mtn >= NTILES) break;
        __syncthreads();                              // WAR: done reading As
        writeA_lds(Asb, arow, akseg, buf);
        mt = mtn; mtn += mstep;
        __syncthreads();                              // RAW: As(new) visible
        if (mtn < NTILES) loadA_raw(A, norm, mtn, arow, akseg, buf);
    }
}

// ---------------- agg layer 1: bf16 in (F=256), bf16 out. Full row per wave,
// 8-deep + 4-deep + scalar unroll. h1 = relu(agg*norm_dst+b1)*norm_src; pad rows zero.
__global__ __launch_bounds__(256) void agg1_kernel(const unsigned short* __restrict__ H,
                                                   const int* __restrict__ row_ptr,
                                                   const int* __restrict__ csr_src,
                                                   const float* __restrict__ norm_dst,
                                                   const float* __restrict__ norm_src,
                                                   const float* __restrict__ bias,
                                                   unsigned short* __restrict__ out) {
    const int F = 256;
    int node = blockIdx.x * 4 + (threadIdx.x >> 6);
    int lane = threadIdx.x & 63;
    int f0 = lane * 4;
    if (node >= NNODES) {
        if (node < MPAD) {
            ushort4 z = {0, 0, 0, 0};
            *(ushort4*)(out + (size_t)node * F + f0) = z;
        }
        return;
    }
    int e0 = row_ptr[node];
    int e1 = row_ptr[node + 1];

    float acc0 = 0.f, acc1 = 0.f, acc2 = 0.f, acc3 = 0.f;
    const unsigned short* Hl = H + f0;

    int e = e0;
    for (; e + 7 < e1; e += 8) {
        ushort4 v[8];
#pragma unroll
        for (int u = 0; u < 8; ++u)
            v[u] = *(const ushort4*)(Hl + (size_t)csr_src[e + u] * F);
#pragma unroll
        for (int u = 0; u < 8; ++u) {
            acc0 += bf2f(v[u].x); acc1 += bf2f(v[u].y);
            acc2 += bf2f(v[u].z); acc3 += bf2f(v[u].w);
        }
    }
    for (; e + 3 < e1; e += 4) {
        ushort4 v[4];
#pragma unroll
        for (int u = 0; u < 4; ++u)
            v[u] = *(const ushort4*)(Hl + (size_t)csr_src[e + u] * F);
#pragma unroll
        for (int u = 0; u < 4; ++u) {
            acc0 += bf2f(v[u].x); acc1 += bf2f(v[u].y);
            acc2 += bf2f(v[u].z); acc3 += bf2f(v[u].w);
        }
    }
    for (; e < e1; ++e) {
        ushort4 v = *(const ushort4*)(Hl + (size_t)csr_src[e] * F);
        acc0 += bf2f(v.x); acc1 += bf2f(v.y); acc2 += bf2f(v.z); acc3 += bf2f(v.w);
    }

    float nd = norm_dst[node];
    float ns = norm_src[node];
    float o0 = fmaxf(fmaf(acc0, nd, bias[f0 + 0]), 0.0f) * ns;
    float o1 = fmaxf(fmaf(acc1, nd, bias[f0 + 1]), 0.0f) * ns;
    float o2 = fmaxf(fmaf(acc2, nd, bias[f0 + 2]), 0.0f) * ns;
    float o3 = fmaxf(fmaf(acc3, nd, bias[f0 + 3]), 0.0f) * ns;
    ushort4 o;
    o.x = f2bf(o0); o.y = f2bf(o1); o.z = f2bf(o2); o.w = f2bf(o3);
    *(ushort4*)(out + (size_t)node * F + f0) = o;
}

// ---------------- agg layer 2: bf16 in (F=128), fp32 out, no relu. Half-wave per node. ----
__global__ __launch_bounds__(256) void agg2_kernel(const unsigned short* __restrict__ H,
                                                   const int* __restrict__ row_ptr,
                                                   const int* __restrict__ csr_src,
                                                   const float* __restrict__ norm_dst,
                                                   const float* __restrict__ bias,
                                                   float* __restrict__ out) {
    const int F = 128;
    int node = blockIdx.x * 8 + (threadIdx.x >> 5);
    if (node >= NNODES) return;
    int lane = threadIdx.x & 31;
    int f0 = lane * 4;
    int e0 = row_ptr[node];
    int e1 = row_ptr[node + 1];

    float acc0 = 0.f, acc1 = 0.f, acc2 = 0.f, acc3 = 0.f;
    const unsigned short* Hl = H + f0;

    int e = e0;
    for (; e + 7 < e1; e += 8) {
        ushort4 v[8];
#pragma unroll
        for (int u = 0; u < 8; ++u)
            v[u] = *(const ushort4*)(Hl + (size_t)csr_src[e + u] * F);
#pragma unroll
        for (int u = 0; u < 8; ++u) {
            acc0 += bf2f(v[u].x); acc1 += bf2f(v[u].y);
            acc2 += bf2f(v[u].z); acc3 += bf2f(v[u].w);
        }
    }
    for (; e + 3 < e1; e += 4) {
        ushort4 v[4];
#pragma unroll
        for (int u = 0; u < 4; ++u)
            v[u] = *(const ushort4*)(Hl + (size_t)csr_src[e + u] * F);
#pragma unroll
        for (int u = 0; u < 4; ++u) {
            acc0 += bf2f(v[u].x); acc1 += bf2f(v[u].y);
            acc2 += bf2f(v[u].z); acc3 += bf2f(v[u].w);
        }
    }
    for (; e < e1; ++e) {
        ushort4 v = *(const ushort4*)(Hl + (size_t)csr_src[e] * F);
        acc0 += bf2f(v.x); acc1 += bf2f(v.y); acc2 += bf2f(v.z); acc3 += bf2f(v.w);
    }

    float nd = norm_dst[node];
    float4 o;
    o.x = fmaf(acc0, nd, bias[f0 + 0]);
    o.y = fmaf(acc1, nd, bias[f0 + 1]);
    o.z = fmaf(acc2, nd, bias[f0 + 2]);
    o.w = fmaf(acc3, nd, bias[f0 + 3]);
    *(float4*)(out + (size_t)node * F + f0) = o;
}

// ---------------- launch ----------------
extern "C" void kernel_launch(void* const* d_in, const int* in_sizes, int n_in,
                              void* d_out, int out_size, void* d_ws, size_t ws_size,
                              hipStream_t stream) {
    const float* x   = (const float*)d_in[0];
    const int*   src = (const int*)d_in[1];
    const int*   dst = (const int*)d_in[2];
    const float* W1  = (const float*)d_in[3];
    const float* b1  = (const float*)d_in[4];
    const float* W2  = (const float*)d_in[5];
    const float* b2  = (const float*)d_in[6];
    float* out = (float*)d_out;

    char* ws = (char*)d_ws;
    size_t off = 0;
    auto alloc = [&](size_t bytes) {
        char* p = ws + off;
        off += (bytes + 255) & ~(size_t)255;
        return p;
    };
    float* norm_src  = (float*)alloc(NNODES * 4);
    float* norm_dst  = (float*)alloc(NNODES * 4);
    int*   cell      = (int*)alloc((size_t)NSCAN * 4);
    int*   ssum      = (int*)alloc(512 * 4);
    unsigned int*  tmp1 = (unsigned int*)alloc((size_t)NEDGES * 4);
    unsigned char* tmp2 = (unsigned char*)alloc((size_t)NEDGES);
    int*   row_ptr   = (int*)alloc((NNODES + 16) * 4);
    int*   csr_src   = (int*)alloc(NEDGES * 4);
    unsigned short* h   = (unsigned short*)alloc((size_t)MPAD * FH * 2);
    unsigned short* h1  = (unsigned short*)alloc((size_t)MPAD * FH * 2);
    unsigned short* Wt1 = (unsigned short*)alloc((size_t)FH * KDIM * 2);
    unsigned short* Wt2 = (unsigned short*)alloc((size_t)FOUT * KDIM * 2);
    unsigned short* h2  = h;

    l1_count_cast<<<NB1 + 96, 256, 0, stream>>>(src, dst, cell, W1, Wt1, W2, Wt2);
    scanA<<<SCANB, 512, 0, stream>>>(cell, ssum, NSCAN);
    scanB<<<1, 512, 0, stream>>>(ssum, SCANB);
    scanC<<<SCANB, 512, 0, stream>>>(cell, ssum, NSCAN);
    l1_scatter<<<NB1, 256, 0, stream>>>(src, dst, cell, tmp1, tmp2);
    l2_both<<<2 * NBUCK, 256, 0, stream>>>(tmp1, tmp2, cell, row_ptr, norm_dst, norm_src, csr_src);

    // layer 1: h = bf16((x*norm_src) @ W1) — B-resident, 2 col-panels XCD-paired
    gemm_bres<float, true, 2><<<512, 512, 0, stream>>>(x, Wt1, norm_src, h);
    agg1_kernel<<<MPAD / 4, 256, 0, stream>>>(h, row_ptr, csr_src, norm_dst, norm_src, b1, h1);

    // layer 2 — B-resident, single 128-col panel
    gemm_bres<unsigned short, false, 1><<<256, 512, 0, stream>>>(h1, Wt2, nullptr, h2);
    agg2_kernel<<<(NNODES + 7) / 8, 256, 0, stream>>>(h2, row_ptr, csr_src, norm_dst, b2, out);
}

// Round 5
// 252.672 us; speedup vs baseline: 1.1348x; 1.0625x over previous
//
#include <hip/hip_runtime.h>

#define NNODES 50000
#define MPAD   50048    // padded to multiple of 64 for MFMA tiles; row 50000.. are zero pads
#define NEDGES 800000
#define KDIM   256      // in/hidden feature dim (GEMM K)
#define FH     256      // hidden feats
#define FOUT   128      // out feats

// ---- counting-sort geometry ----
#define SHIFT  8
#define NBUCK  196              // ceil(50000/256); max dst>>8 = 195
#define NB1    200              // level-1 blocks
#define EPB    4000             // edges per level-1 block (NB1*EPB == NEDGES)

typedef __bf16 bf16x8 __attribute__((ext_vector_type(8)));
typedef float floatx4 __attribute__((ext_vector_type(4)));

// ---------------- bf16 helpers (RNE) ----------------
__device__ __forceinline__ float bf2f(unsigned short u) {
    union { unsigned int i; float f; } v;
    v.i = ((unsigned int)u) << 16;
    return v.f;
}
__device__ __forceinline__ unsigned short f2bf(float f) {
    union { float f; unsigned int i; } v;
    v.f = f;
    unsigned int r = v.i + 0x7FFFu + ((v.i >> 16) & 1u);
    return (unsigned short)(r >> 16);
}

// ============ P1: per-block counting sort, block-major output (no global scan needed)
// blocks 0..NB1-1: sort 4000 edges by dst-bucket (and src-bucket) into tmp1/tmp2[b*EPB..],
//                  export per-(bucket,block) exclusive offsets exD_arr/exS_arr.
// blocks NB1..NB1+95: W1/W2 [K][N] -> Wt [N][K] bf16 transpose.
__global__ __launch_bounds__(256) void l1_sort_cast(const int* __restrict__ src,
                                                    const int* __restrict__ dst,
                                                    unsigned int* __restrict__ tmp1,
                                                    unsigned char* __restrict__ tmp2,
                                                    int* __restrict__ exD_arr,
                                                    int* __restrict__ exS_arr,
                                                    const float* __restrict__ W1,
                                                    unsigned short* __restrict__ Wt1,
                                                    const float* __restrict__ W2,
                                                    unsigned short* __restrict__ Wt2) {
    __shared__ int histD[256], histS[256], exD[256], exS[256];
    __shared__ unsigned int bufD[EPB];
    __shared__ unsigned short bufS[EPB];
    __shared__ float tile[32][33];
    const int tid = threadIdx.x;

    if (blockIdx.x >= NB1) {
        int b = blockIdx.x - NB1;
        const float* W; unsigned short* Wt; int N;
        if (b < 64) { W = W1; Wt = Wt1; N = FH; }
        else        { b -= 64; W = W2; Wt = Wt2; N = FOUT; }
        int kt = (b & 7) * 32;
        int nt = (b >> 3) * 32;
        int tx = tid & 31;
        int ty = tid >> 5;
        for (int r = ty; r < 32; r += 8)
            tile[r][tx] = W[(size_t)(kt + r) * N + nt + tx];
        __syncthreads();
        for (int r = ty; r < 32; r += 8)
            Wt[(size_t)(nt + r) * KDIM + kt + tx] = f2bf(tile[tx][r]);
        return;
    }

    const int b = blockIdx.x;
    const int base = b * EPB;
    histD[tid] = 0; histS[tid] = 0;
    __syncthreads();
    for (int g = tid; g < EPB / 4; g += 256) {
        uint4 s4 = *(const uint4*)(src + base + g * 4);
        uint4 d4 = *(const uint4*)(dst + base + g * 4);
        atomicAdd(&histD[d4.x >> SHIFT], 1);
        atomicAdd(&histD[d4.y >> SHIFT], 1);
        atomicAdd(&histD[d4.z >> SHIFT], 1);
        atomicAdd(&histD[d4.w >> SHIFT], 1);
        atomicAdd(&histS[s4.x >> SHIFT], 1);
        atomicAdd(&histS[s4.y >> SHIFT], 1);
        atomicAdd(&histS[s4.z >> SHIFT], 1);
        atomicAdd(&histS[s4.w >> SHIFT], 1);
    }
    __syncthreads();
    int vD = histD[tid], vS = histS[tid];
    exD[tid] = vD; exS[tid] = vS;
    __syncthreads();
    for (int off = 1; off < 256; off <<= 1) {
        int tD = (tid >= off) ? exD[tid - off] : 0;
        int tS = (tid >= off) ? exS[tid - off] : 0;
        __syncthreads();
        exD[tid] += tD; exS[tid] += tS;
        __syncthreads();
    }
    int eD = exD[tid] - vD, eS = exS[tid] - vS;
    exD_arr[tid * NB1 + b] = eD;     // rows 0..255 (>=NBUCK rows used as k+1 sentinels)
    exS_arr[tid * NB1 + b] = eS;
    __syncthreads();
    histD[tid] = eD; histS[tid] = eS;   // cursors
    __syncthreads();
    for (int g = tid; g < EPB / 4; g += 256) {
        uint4 s4 = *(const uint4*)(src + base + g * 4);
        uint4 d4 = *(const uint4*)(dst + base + g * 4);
        unsigned int ss[4] = {s4.x, s4.y, s4.z, s4.w};
        unsigned int dd[4] = {d4.x, d4.y, d4.z, d4.w};
#pragma unroll
        for (int j = 0; j < 4; ++j) {
            int p = atomicAdd(&histD[dd[j] >> SHIFT], 1);
            bufD[p] = (ss[j] << 16) | dd[j];
            int q = atomicAdd(&histS[ss[j] >> SHIFT], 1);
            bufS[q] = (unsigned short)ss[j];
        }
    }
    __syncthreads();
    for (int e = tid; e < EPB; e += 256) tmp1[base + e] = bufD[e];
    for (int e = tid; e < EPB; e += 256) tmp2[base + e] = (unsigned char)(bufS[e] & 255u);
}

// ============ P2: per-bucket finalize. dst side (blocks 0..NBUCK-1): counts, row_ptr,
// norm_dst, csr scatter. src side (NBUCK..2*NBUCK-1): counts -> norm_src.
// Bucket base = sum over blocks of exD_arr[k][b] (= #edges with bucket < k).
__global__ __launch_bounds__(256) void l2_both(const unsigned int* __restrict__ tmp1,
                                               const unsigned char* __restrict__ tmp2,
                                               const int* __restrict__ exD_arr,
                                               const int* __restrict__ exS_arr,
                                               int* __restrict__ row_ptr,
                                               float* __restrict__ norm_dst,
                                               float* __restrict__ norm_src,
                                               int* __restrict__ csr_src) {
    __shared__ int cnt[256], ofs[256], cur[256], red[256];
    __shared__ int segoff[NB1], seglen[NB1];
    const int tid = threadIdx.x;

    if (blockIdx.x >= NBUCK) {
        // ---- src side ----
        const int k = blockIdx.x - NBUCK;
        if (tid < NB1) {
            int e0 = exS_arr[k * NB1 + tid];
            segoff[tid] = tid * EPB + e0;
            seglen[tid] = exS_arr[(k + 1) * NB1 + tid] - e0;
        }
        cnt[tid] = 0;
        __syncthreads();
        if (tid < NB1) {
            int so = segoff[tid], sl = seglen[tid];
            for (int i = 0; i < sl; ++i)
                atomicAdd(&cnt[tmp2[so + i]], 1);
        }
        __syncthreads();
        int node = k * 256 + tid;
        if (node < NNODES) {
            int d = cnt[tid] < 1 ? 1 : cnt[tid];
            norm_src[node] = 1.0f / sqrtf((float)d);
        }
        return;
    }

    // ---- dst side ----
    const int k = blockIdx.x;
    int e0v = 0;
    if (tid < NB1) {
        e0v = exD_arr[k * NB1 + tid];
        segoff[tid] = tid * EPB + e0v;
        seglen[tid] = exD_arr[(k + 1) * NB1 + tid] - e0v;
    }
    red[tid] = (tid < NB1) ? e0v : 0;
    cnt[tid] = 0;
    __syncthreads();
    for (int off = 128; off > 0; off >>= 1) {
        if (tid < off) red[tid] += red[tid + off];
        __syncthreads();
    }
    const int base = red[0];
    if (tid < NB1) {
        int so = segoff[tid], sl = seglen[tid];
        for (int i = 0; i < sl; ++i)
            atomicAdd(&cnt[tmp1[so + i] & 255u], 1);
    }
    __syncthreads();
    int v = cnt[tid];
    ofs[tid] = v;
    __syncthreads();
    for (int off = 1; off < 256; off <<= 1) {
        int t = (tid >= off) ? ofs[tid - off] : 0;
        __syncthreads();
        ofs[tid] += t;
        __syncthreads();
    }
    int excl = ofs[tid] - v;
    int node = k * 256 + tid;
    if (node < NNODES) {
        row_ptr[node] = base + excl;
        int d = v < 1 ? 1 : v;
        norm_dst[node] = 1.0f / sqrtf((float)d);
    }
    cur[tid] = base + excl;
    if (k == 0 && tid == 0) row_ptr[NNODES] = NEDGES;
    __syncthreads();
    if (tid < NB1) {
        int so = segoff[tid], sl = seglen[tid];
        for (int i = 0; i < sl; ++i) {
            unsigned int p = tmp1[so + i];
            int pos = atomicAdd(&cur[p & 255u], 1);
            csr_src[pos] = (int)(p >> 16);
        }
    }
}

// ================= B-resident GEMM (unchanged structure; now writes all MPAD rows,
// pad rows compute to zero -> zero-row clamp target for the agg kernels) =================
struct arawF { float4 v[8]; float sc; };
struct arawU { uint4 v[4]; };
template <typename TA> struct rawsel;
template <> struct rawsel<float> { using type = arawF; };
template <> struct rawsel<unsigned short> { using type = arawU; };

__device__ __forceinline__ void loadA_raw(const float* A, const float* norm,
                                          int mt, int arow, int akseg, arawF& r) {
    int row = mt * 64 + arow;
    if (row < NNODES) {
        const float* p = A + (size_t)row * KDIM + akseg;
#pragma unroll
        for (int j = 0; j < 8; ++j) r.v[j] = *(const float4*)(p + j * 4);
        r.sc = norm[row];
    } else {
        float4 z = {0.f, 0.f, 0.f, 0.f};
#pragma unroll
        for (int j = 0; j < 8; ++j) r.v[j] = z;
        r.sc = 0.f;
    }
}
__device__ __forceinline__ void loadA_raw(const unsigned short* A, const float*,
                                          int mt, int arow, int akseg, arawU& r) {
    const unsigned short* p = A + (size_t)(mt * 64 + arow) * KDIM + akseg;  // rows < MPAD, zero-padded
#pragma unroll
    for (int j = 0; j < 4; ++j) r.v[j] = *(const uint4*)(p + j * 8);
}
__device__ __forceinline__ void writeA_lds(char* Asb, int arow, int akseg, const arawF& r) {
    const int s = (arow & 7) << 4;
    const int base = arow * 512;
#pragma unroll
    for (int j = 0; j < 4; ++j) {
        union { uint4 u; unsigned short h[8]; } o;
        float4 a = r.v[2 * j], b = r.v[2 * j + 1];
        o.h[0] = f2bf(a.x * r.sc); o.h[1] = f2bf(a.y * r.sc);
        o.h[2] = f2bf(a.z * r.sc); o.h[3] = f2bf(a.w * r.sc);
        o.h[4] = f2bf(b.x * r.sc); o.h[5] = f2bf(b.y * r.sc);
        o.h[6] = f2bf(b.z * r.sc); o.h[7] = f2bf(b.w * r.sc);
        *(uint4*)(Asb + base + (((akseg + j * 8) * 2) ^ s)) = o.u;
    }
}
__device__ __forceinline__ void writeA_lds(char* Asb, int arow, int akseg, const arawU& r) {
    const int s = (arow & 7) << 4;
    const int base = arow * 512;
#pragma unroll
    for (int j = 0; j < 4; ++j)
        *(uint4*)(Asb + base + (((akseg + j * 8) * 2) ^ s)) = r.v[j];
}

template <typename TA, bool SCALE, int NPANEL>
__global__ __launch_bounds__(512) void gemm_bres(const TA* __restrict__ A,
                                                 const unsigned short* __restrict__ Bt,
                                                 const float* __restrict__ norm,
                                                 unsigned short* __restrict__ C) {
    constexpr int N = 128 * NPANEL;
    constexpr int NTILES = MPAD / 64;
    __shared__ __align__(16) unsigned short Bs[128 * 256];   // 64KB, [col][k] swizzled
    __shared__ __align__(16) unsigned short As[64 * 256];    // 32KB, [row][k] swizzled
    char* Bsb = (char*)Bs;
    char* Asb = (char*)As;

    const int tid = threadIdx.x;
    const int lane = tid & 63;
    const int wave = tid >> 6;

    int col0, mt0, mstep;
    if (NPANEL == 2) {
        col0 = ((blockIdx.x >> 3) & 1) * 128;
        mt0 = ((blockIdx.x >> 4) << 3) + (blockIdx.x & 7);
        mstep = gridDim.x >> 1;
    } else {
        col0 = 0;
        mt0 = blockIdx.x;
        mstep = gridDim.x;
    }

    {
        int col = tid >> 2;
        int kq = (tid & 3) * 64;
        const unsigned short* bg = Bt + (size_t)(col0 + col) * KDIM + kq;
        const int s = (col & 7) << 4;
        const int base = col * 512;
#pragma unroll
        for (int j = 0; j < 8; ++j) {
            uint4 v = *(const uint4*)(bg + j * 8);
            *(uint4*)(Bsb + base + (((kq + j * 8) * 2) ^ s)) = v;
        }
    }

    const int arow = tid >> 3;
    const int akseg = (tid & 7) * 32;

    typename rawsel<TA>::type buf;
    loadA_raw(A, norm, mt0, arow, akseg, buf);
    writeA_lds(Asb, arow, akseg, buf);
    __syncthreads();
    int mt = mt0, mtn = mt0 + mstep;
    if (mtn < NTILES) loadA_raw(A, norm, mtn, arow, akseg, buf);

    const int wn = wave & 3, wm = wave >> 2;
    const int ar = lane & 15;
    const int fkb = (lane >> 4) << 4;
    const int rA0 = wm * 32 + ar,  rA1 = rA0 + 16;
    const int cB0 = wn * 32 + ar,  cB1 = cB0 + 16;
    const int aO0 = rA0 * 512, aS0 = (rA0 & 7) << 4;
    const int aO1 = rA1 * 512, aS1 = (rA1 & 7) << 4;
    const int bO0 = cB0 * 512, bS0 = (cB0 & 7) << 4;
    const int bO1 = cB1 * 512, bS1 = (cB1 & 7) << 4;
    const int rb = (lane >> 4) << 2, cc = lane & 15;

    for (;;) {
        floatx4 a00 = {}, a01 = {}, a10 = {}, a11 = {};
#pragma unroll
        for (int kk = 0; kk < 8; ++kk) {
            const int kb = kk * 64 + fkb;
            bf16x8 fa0 = *(const bf16x8*)(Asb + aO0 + (kb ^ aS0));
            bf16x8 fa1 = *(const bf16x8*)(Asb + aO1 + (kb ^ aS1));
            bf16x8 fb0 = *(const bf16x8*)(Bsb + bO0 + (kb ^ bS0));
            bf16x8 fb1 = *(const bf16x8*)(Bsb + bO1 + (kb ^ bS1));
            a00 = __builtin_amdgcn_mfma_f32_16x16x32_bf16(fa0, fb0, a00, 0, 0, 0);
            a01 = __builtin_amdgcn_mfma_f32_16x16x32_bf16(fa0, fb1, a01, 0, 0, 0);
            a10 = __builtin_amdgcn_mfma_f32_16x16x32_bf16(fa1, fb0, a10, 0, 0, 0);
            a11 = __builtin_amdgcn_mfma_f32_16x16x32_bf16(fa1, fb1, a11, 0, 0, 0);
        }
        {
            const int mBase = mt * 64 + wm * 32 + rb;
            const int cBase = col0 + wn * 32 + cc;
#pragma unroll
            for (int r = 0; r < 4; ++r) {
                int m = mBase + r;
                C[(size_t)m * N + cBase]      = f2bf(a00[r]);
                C[(size_t)m * N + cBase + 16] = f2bf(a01[r]);
                int m2 = m + 16;
                C[(size_t)m2 * N + cBase]      = f2bf(a10[r]);
                C[(size_t)m2 * N + cBase + 16] = f2bf(a11[r]);
            }
        }
        if (mtn >= NTILES) break;
        __syncthreads();
        writeA_lds(Asb, arow, akseg, buf);
        mt = mtn; mtn += mstep;
        __syncthreads();
        if (mtn < NTILES) loadA_raw(A, norm, mtn, arow, akseg, buf);
    }
}

// ============ agg layer 1: F=256, 32 lanes/node (wave = 2 nodes), 16B/lane loads.
// One dwordx4 gather serves 2 edges. Uniform trip count = max(degA,degB); expired
// slots read the zero pad row (NNODES). Indices via scalar path (readfirstlane'd bases).
__global__ __launch_bounds__(256) void agg1_kernel(const unsigned short* __restrict__ H,
                                                   const int* __restrict__ row_ptr,
                                                   const int* __restrict__ csr_src,
                                                   const float* __restrict__ norm_dst,
                                                   const float* __restrict__ norm_src,
                                                   const float* __restrict__ bias,
                                                   unsigned short* __restrict__ out) {
    const int F = 256;
    const int tid = threadIdx.x;
    const int lane = tid & 63;
    const int half = lane >> 5;
    const int f0 = (lane & 31) * 8;
    const int nA = __builtin_amdgcn_readfirstlane(blockIdx.x * 8 + (tid >> 6) * 2);
    const int node = nA + half;

    const int rp0 = row_ptr[nA < NNODES ? nA : NNODES];
    const int rp1 = row_ptr[nA + 1 < NNODES ? nA + 1 : NNODES];
    const int rp2 = row_ptr[nA + 2 < NNODES ? nA + 2 : NNODES];
    const int degA = rp1 - rp0, degB = rp2 - rp1;
    const int nIter = degA > degB ? degA : degB;

    const unsigned short* Hl = H + f0;
    float acc[8] = {};

    for (int it = 0; it < nIter; it += 4) {
        int ix[4];
#pragma unroll
        for (int u = 0; u < 4; ++u) {
            int iA = csr_src[rp0 + it + u];
            int iB = csr_src[rp1 + it + u];
            iA = (it + u < degA) ? iA : NNODES;
            iB = (it + u < degB) ? iB : NNODES;
            ix[u] = half ? iB : iA;
        }
        uint4 v[4];
#pragma unroll
        for (int u = 0; u < 4; ++u)
            v[u] = *(const uint4*)(Hl + (size_t)ix[u] * F);
#pragma unroll
        for (int u = 0; u < 4; ++u) {
            const unsigned short* pv = (const unsigned short*)&v[u];
#pragma unroll
            for (int j = 0; j < 8; ++j) acc[j] += bf2f(pv[j]);
        }
    }

    float nd = 0.f, ns = 0.f;
    if (node < NNODES) { nd = norm_dst[node]; ns = norm_src[node]; }
    float4 b0 = *(const float4*)(bias + f0);
    float4 b1v = *(const float4*)(bias + f0 + 4);
    float bb[8] = {b0.x, b0.y, b0.z, b0.w, b1v.x, b1v.y, b1v.z, b1v.w};
    union { uint4 u; unsigned short s[8]; } o;
#pragma unroll
    for (int j = 0; j < 8; ++j)
        o.s[j] = f2bf(fmaxf(fmaf(acc[j], nd, bb[j]), 0.f) * ns);
    *(uint4*)(out + (size_t)node * F + f0) = o.u;   // node < MPAD by grid; pads get zeros (ns=0)
}

// ============ agg layer 2: F=128, 16 lanes/node (wave = 4 nodes), 16B/lane loads,
// fp32 out, no relu. Same zero-row clamp scheme.
__global__ __launch_bounds__(256) void agg2_kernel(const unsigned short* __restrict__ H,
                                                   const int* __restrict__ row_ptr,
                                                   const int* __restrict__ csr_src,
                                                   const float* __restrict__ norm_dst,
                                                   const float* __restrict__ bias,
                                                   float* __restrict__ out) {
    const int F = 128;
    const int tid = threadIdx.x;
    const int lane = tid & 63;
    const int q = lane >> 4;
    const int f0 = (lane & 15) * 8;
    const int n0 = __builtin_amdgcn_readfirstlane(blockIdx.x * 16 + (tid >> 6) * 4);
    const int node = n0 + q;

    int rp[5];
#pragma unroll
    for (int j = 0; j < 5; ++j) rp[j] = row_ptr[(n0 + j) < NNODES ? (n0 + j) : NNODES];
    int dg[4];
    int nIter = 0;
#pragma unroll
    for (int j = 0; j < 4; ++j) { dg[j] = rp[j + 1] - rp[j]; nIter = dg[j] > nIter ? dg[j] : nIter; }

    const unsigned short* Hl = H + f0;
    float acc[8] = {};

    for (int it = 0; it < nIter; it += 4) {
        int ix[4];
#pragma unroll
        for (int u = 0; u < 4; ++u) {
            int i0 = csr_src[rp[0] + it + u];
            int i1 = csr_src[rp[1] + it + u];
            int i2 = csr_src[rp[2] + it + u];
            int i3 = csr_src[rp[3] + it + u];
            i0 = (it + u < dg[0]) ? i0 : NNODES;
            i1 = (it + u < dg[1]) ? i1 : NNODES;
            i2 = (it + u < dg[2]) ? i2 : NNODES;
            i3 = (it + u < dg[3]) ? i3 : NNODES;
            int ilo = (q & 1) ? i1 : i0;
            int ihi = (q & 1) ? i3 : i2;
            ix[u] = (q & 2) ? ihi : ilo;
        }
        uint4 v[4];
#pragma unroll
        for (int u = 0; u < 4; ++u)
            v[u] = *(const uint4*)(Hl + (size_t)ix[u] * F);
#pragma unroll
        for (int u = 0; u < 4; ++u) {
            const unsigned short* pv = (const unsigned short*)&v[u];
#pragma unroll
            for (int j = 0; j < 8; ++j) acc[j] += bf2f(pv[j]);
        }
    }

    if (node < NNODES) {
        float nd = norm_dst[node];
        float4 o1, o2;
        o1.x = fmaf(acc[0], nd, bias[f0 + 0]);
        o1.y = fmaf(acc[1], nd, bias[f0 + 1]);
        o1.z = fmaf(acc[2], nd, bias[f0 + 2]);
        o1.w = fmaf(acc[3], nd, bias[f0 + 3]);
        o2.x = fmaf(acc[4], nd, bias[f0 + 4]);
        o2.y = fmaf(acc[5], nd, bias[f0 + 5]);
        o2.z = fmaf(acc[6], nd, bias[f0 + 6]);
        o2.w = fmaf(acc[7], nd, bias[f0 + 7]);
        *(float4*)(out + (size_t)node * F + f0) = o1;
        *(float4*)(out + (size_t)node * F + f0 + 4) = o2;
    }
}

// ---------------- launch ----------------
extern "C" void kernel_launch(void* const* d_in, const int* in_sizes, int n_in,
                              void* d_out, int out_size, void* d_ws, size_t ws_size,
                              hipStream_t stream) {
    const float* x   = (const float*)d_in[0];
    const int*   src = (const int*)d_in[1];
    const int*   dst = (const int*)d_in[2];
    const float* W1  = (const float*)d_in[3];
    const float* b1  = (const float*)d_in[4];
    const float* W2  = (const float*)d_in[5];
    const float* b2  = (const float*)d_in[6];
    float* out = (float*)d_out;

    char* ws = (char*)d_ws;
    size_t off = 0;
    auto alloc = [&](size_t bytes) {
        char* p = ws + off;
        off += (bytes + 255) & ~(size_t)255;
        return p;
    };
    float* norm_src  = (float*)alloc(NNODES * 4);
    float* norm_dst  = (float*)alloc(NNODES * 4);
    int*   exD_arr   = (int*)alloc((size_t)256 * NB1 * 4);
    int*   exS_arr   = (int*)alloc((size_t)256 * NB1 * 4);
    unsigned int*  tmp1 = (unsigned int*)alloc((size_t)NEDGES * 4);
    unsigned char* tmp2 = (unsigned char*)alloc((size_t)NEDGES);
    int*   row_ptr   = (int*)alloc((NNODES + 16) * 4);
    int*   csr_src   = (int*)alloc((size_t)(NEDGES + 256) * 4);
    unsigned short* h   = (unsigned short*)alloc((size_t)MPAD * FH * 2);
    unsigned short* h1  = (unsigned short*)alloc((size_t)MPAD * FH * 2);
    unsigned short* Wt1 = (unsigned short*)alloc((size_t)FH * KDIM * 2);
    unsigned short* Wt2 = (unsigned short*)alloc((size_t)FOUT * KDIM * 2);
    unsigned short* h2  = h;

    l1_sort_cast<<<NB1 + 96, 256, 0, stream>>>(src, dst, tmp1, tmp2, exD_arr, exS_arr,
                                               W1, Wt1, W2, Wt2);
    l2_both<<<2 * NBUCK, 256, 0, stream>>>(tmp1, tmp2, exD_arr, exS_arr,
                                           row_ptr, norm_dst, norm_src, csr_src);

    // layer 1: h = bf16((x*norm_src) @ W1) — B-resident, 2 col-panels XCD-paired
    gemm_bres<float, true, 2><<<512, 512, 0, stream>>>(x, Wt1, norm_src, h);
    agg1_kernel<<<MPAD / 8, 256, 0, stream>>>(h, row_ptr, csr_src, norm_dst, norm_src, b1, h1);

    // layer 2 — B-resident, single 128-col panel
    gemm_bres<unsigned short, false, 1><<<256, 512, 0, stream>>>(h1, Wt2, nullptr, h2);
    agg2_kernel<<<(NNODES + 15) / 16, 256, 0, stream>>>(h2, row_ptr, csr_src, norm_dst, b2, out);
}